// Round 23
// baseline (292.910 us; speedup 1.0000x reference)
//
#include <hip/hip_runtime.h>
#include <math.h>

#define BATCH 65536
#define LEAD  24
#define MEM   51
#define NPRED 6
#define HID   128
#define TB    64
#define NBLK  4
#define OUTC  960
#define XTOTF (BATCH * LEAD * MEM)

#define HSTR  136                 // bf16 plane row stride (shorts)
#define HPLW  (16 * HSTR)         // shorts per wave-plane (16 rows)
#define CSTRW 160                 // wave-kernel cbuf stride; 4 arenas = 40960 B -> 4 blocks/CU
#define ARENA_B (16 * CSTRW * 4)  // 10240 B
#define CSTR  165                 // legacy fallback cbuf stride
#define HPL   (64 * HSTR)         // legacy fallback plane size
// d_ws: [0, 786432) weights (frag-major) | [+FEAT_BYTES) feat f32 [BATCH][64]
#define WS_BYTES   786432
#define FEAT_BYTES ((size_t)BATCH * 64 * 4)
#define WS_FUSED   ((size_t)WS_BYTES + FEAT_BYTES)

typedef float f32x4 __attribute__((ext_vector_type(4)));
typedef short s16x8 __attribute__((ext_vector_type(8)));

// Fast-math forms (v_exp/v_log/v_rcp): rel err ~1e-6/op; absmax headroom is 8x.
__device__ __forceinline__ float sp_softplus(float z) {
    return fmaxf(z, 0.0f) + __logf(1.0f + __expf(-fabsf(z)));
}
__device__ __forceinline__ float silu_f(float z) {
    return __fdividef(z, 1.0f + __expf(-z));
}
__device__ __forceinline__ void bf16split(float x, unsigned &hi, unsigned &lo) {
    unsigned xb = __float_as_uint(x);
    hi = xb >> 16;
    float fhi = __uint_as_float(xb & 0xFFFF0000u);
    lo = __float_as_uint(x - fhi) >> 16;
}
__device__ __forceinline__ float bf16re(short u) {
    return __uint_as_float(((unsigned)(unsigned short)u) << 16);
}

// ---------------- prep: transpose + hi/lo split, fragment-major ----------------
__global__ __launch_bounds__(256) void prep_kernel(
    const float* __restrict__ W_in,
    const float* __restrict__ Ws0, const float* __restrict__ Ws1,
    const float* __restrict__ Ws2, const float* __restrict__ Ws3,
    const float* __restrict__ W_out, unsigned short* __restrict__ wq)
{
    int idx = blockIdx.x * 256 + threadIdx.x;
    float val; int ih, il;
    if (idx < 8192) {                  // W_inT: tile(8) x kt(2) x lane x j
        int tile = idx >> 10, rem = idx & 1023;
        int kk = rem >> 9, lane = (rem >> 3) & 63, j = rem & 7;
        int col = tile * 16 + (lane & 15);
        int k   = kk * 32 + (lane >> 4) * 8 + j;
        val = (k < 54) ? W_in[k * HID + col] : 0.0f;
        ih = idx; il = 8192 + idx;
    } else if (idx < 73728) {          // WsT: 4 layers x tile(8) x kt(4)
        int r = idx - 8192, l = r >> 14, r2 = r & 16383;
        int tile = r2 >> 11, rem = r2 & 2047;
        int kk = rem >> 9, lane = (rem >> 3) & 63, j = rem & 7;
        int col = tile * 16 + (lane & 15);
        int k   = kk * 32 + (lane >> 4) * 8 + j;
        const float* W = (l == 0) ? Ws0 : (l == 1) ? Ws1 : (l == 2) ? Ws2 : Ws3;
        val = W[k * HID + col];
        ih = 16384 + l * 32768 + r2; il = ih + 16384;
    } else {                           // W_outT: tile(60) x kt(4)
        int r = idx - 73728;
        int tile = r >> 11, rem = r & 2047;
        int kk = rem >> 9, lane = (rem >> 3) & 63, j = rem & 7;
        int col = tile * 16 + (lane & 15);
        int k   = kk * 32 + (lane >> 4) * 8 + j;
        val = W_out[k * OUTC + col];
        ih = 147456 + r; il = 270336 + r;
    }
    unsigned hi, lo; bf16split(val, hi, lo);
    wq[ih] = (unsigned short)hi;
    wq[il] = (unsigned short)lo;
}

// ---------------- stats: pure-BW kernel, x -> feat[BATCH][64] (full precision) ----------------
__global__ __launch_bounds__(256, 8) void stats_kernel(
    const float* __restrict__ x, const float* __restrict__ p,
    float* __restrict__ feat)
{
    const int t   = threadIdx.x;
    const int sub = t & 15;
    const int g0  = blockIdx.x * 16 + (t >> 4);
    const int NG  = gridDim.x * 16;
    for (int row = g0; row < BATCH * LEAD; row += NG) {
        int D  = row * MEM;
        int C0 = D >> 2, o0 = D & 3;
        int basei = 4 * sub - o0;
        float s = 0.f, ss = 0.f;
        if (basei < 51) {
            int ci = C0 + sub;
            if (4 * ci + 4 <= XTOTF) {
                f32x4 v = *(const f32x4*)(x + 4 * ci);
                #pragma unroll
                for (int i = 0; i < 4; ++i) {
                    bool ok = (basei + i >= 0) && (basei + i < 51);
                    float u = ok ? v[i] : 0.0f;
                    s += u; ss += u * u;
                }
            } else {
                #pragma unroll
                for (int i = 0; i < 4; ++i) {
                    int gi = 4 * ci + i;
                    bool ok = (basei + i >= 0) && (basei + i < 51) && (gi < XTOTF);
                    float u = ok ? x[gi] : 0.0f;
                    s += u; ss += u * u;
                }
            }
        }
        s += __shfl_xor(s, 1);  ss += __shfl_xor(ss, 1);
        s += __shfl_xor(s, 2);  ss += __shfl_xor(ss, 2);
        s += __shfl_xor(s, 4);  ss += __shfl_xor(ss, 4);
        s += __shfl_xor(s, 8);  ss += __shfl_xor(ss, 8);
        if (sub == 0) {
            int b = row / LEAD, ld = row - b * LEAD;
            float mv = s / 51.0f;
            float sd = sqrtf(fmaxf((ss - 51.0f * mv * mv) / 50.0f, 0.0f));
            float* fr = feat + (size_t)b * 64;
            fr[2 * ld]     = mv;
            fr[2 * ld + 1] = sd;
        }
    }
    for (size_t idx = (size_t)blockIdx.x * 256 + t; idx < (size_t)BATCH * 16;
         idx += (size_t)gridDim.x * 256) {
        int b = (int)(idx >> 4), c = (int)(idx & 15) + 48;
        feat[(size_t)b * 64 + c] = (c < 54) ? p[(size_t)b * NPRED + (c - 48)] : 0.0f;
    }
}

#define MFMA(a, b, c) __builtin_amdgcn_mfma_f32_16x16x32_bf16((a), (b), (c), 0, 0, 0)

// ---------------- spline body (fast-math; cc may be a register array) ----------------
__device__ __forceinline__ float spline_eval(const float* cc, float ff) {
    float dt_prod = 1.0f;
    #pragma unroll
    for (int blk = 0; blk < NBLK; ++blk) {
        float tk[5], yk[5];
        tk[0] = cc[blk * 10 + 0];
        yk[0] = cc[blk * 10 + 5];
        #pragma unroll
        for (int kk = 1; kk < 5; ++kk) {
            tk[kk] = tk[kk - 1] + 0.001f + sp_softplus(cc[blk * 10 + kk]);
            yk[kk] = yk[kk - 1] + 0.001f + sp_softplus(cc[blk * 10 + 5 + kk]);
        }
        float df[4];
        #pragma unroll
        for (int j = 0; j < 4; ++j) df[j] = __fdividef(yk[j + 1] - yk[j], tk[j + 1] - tk[j]);
        float g02 = __fdividef(yk[2] - yk[0], tk[2] - tk[0]);
        float g13 = __fdividef(yk[3] - yk[1], tk[3] - tk[1]);
        float g24 = __fdividef(yk[4] - yk[2], tk[4] - tk[2]);
        float dd[5];
        dd[0] = __fdividef(df[0] * df[0], g02);
        dd[1] = __fdividef(df[0] * df[1], g02);
        dd[2] = __fdividef(df[1] * df[2], g13);
        dd[3] = __fdividef(df[2] * df[3], g24);
        dd[4] = __fdividef(df[3] * df[3], g24);

        int cnt = (ff > tk[0]) + (ff > tk[1]) + (ff > tk[2]) + (ff > tk[3]) + (ff > tk[4]);
        bool e0 = (cnt == 0), e1 = (cnt == 5);
        int k0 = cnt - 1; k0 = k0 < 0 ? 0 : (k0 > 3 ? 3 : k0);

        float t0v = tk[0], t1v = tk[1], y0v = yk[0], y1v = yk[1], d0v = dd[0], d1v = dd[1];
        #pragma unroll
        for (int j = 1; j < 4; ++j) {
            bool c = (k0 == j);
            t0v = c ? tk[j] : t0v;  t1v = c ? tk[j + 1] : t1v;
            y0v = c ? yk[j] : y0v;  y1v = c ? yk[j + 1] : y1v;
            d0v = c ? dd[j] : d0v;  d1v = c ? dd[j + 1] : d1v;
        }

        float dt_ = t1v - t0v, dy_ = y1v - y0v;
        float s_  = __fdividef(dy_, dt_);
        float e   = __fdividef(ff - t0v, dt_);
        float one_e = 1.0f - e;
        float bb  = d1v + d0v - 2.0f * s_;
        float n0  = dy_ * (s_ * e * e + d0v * e * one_e);
        float n1  = s_ + bb * e * one_e;
        float p_mid = y0v + __fdividef(n0, n1);
        float p_lo  = d0v * ff + (y0v - d0v * t0v);
        float p_hi  = d1v * ff + (y1v - d1v * t1v);
        float val = e0 ? p_lo : (e1 ? p_hi : p_mid);

        float div0 = s_ * s_ * (d1v * e * e + 2.0f * s_ * e * one_e + d0v * one_e * one_e);
        float div1 = n1 * n1;
        float der  = e0 ? d0v : (e1 ? d1v : __fdividef(div0, div1));

        dt_prod *= der;
        ff = val;
    }
    return __expf(-0.5f * ff * ff) * dt_prod * 0.3989422804014327f;  // 1/sqrt(2pi)
}

// ---------------- barrier-free fused kernel: wave-private 16-row pipeline ----------------
// cbuf XOR-swizzle: dword idx ^= (row&7)<<2 -> spline reads 16-way -> 2-way.
// Raw s_barrier (no waitcnt: arenas are wave-private) re-converges the 4 waves
// so their identical B-tile L2 reads coalesce in L1/MSHRs.
__global__ __launch_bounds__(256, 2) void fused_wave_kernel(
    const float* __restrict__ feat, const float* __restrict__ f,
    const float* __restrict__ b_in,
    const float* __restrict__ bs0, const float* __restrict__ bs1,
    const float* __restrict__ bs2, const float* __restrict__ bs3,
    const float* __restrict__ b_out,
    const unsigned short* __restrict__ wq,
    float* __restrict__ out)
{
    __shared__ __align__(16) char smem[4 * ARENA_B];

    const int t    = threadIdx.x;
    const int lane = t & 63;
    const int w    = t >> 6;
    const int lL   = lane & 15;
    const int lH   = lane >> 4;
    const int b0   = blockIdx.x * TB;
    const int r0   = b0 + w * 16;          // this wave's first global row

    short* hi_sh = (short*)(smem + w * ARENA_B);
    short* lo_sh = hi_sh + HPLW;
    float* cbufw = (float*)(smem + w * ARENA_B);
    unsigned* u32p = (unsigned*)hi_sh;

    // -------- phase 0': feat -> wave-private split-bf16 planes --------
    #pragma unroll
    for (int i = 0; i < 4; ++i) {
        int idx = i * 64 + lane;            // 0..255 : 16 rows x 16 chunks
        int r  = idx >> 4, c4 = (idx & 15) * 4;
        f32x4 v = *(const f32x4*)(feat + (size_t)(r0 + r) * 64 + c4);
        unsigned h0, l0, h1, l1, h2, l2, h3, l3;
        bf16split(v[0], h0, l0); bf16split(v[1], h1, l1);
        bf16split(v[2], h2, l2); bf16split(v[3], h3, l3);
        int base = r * HSTR + c4;           // even
        u32p[(base >> 1)]            = h0 | (h1 << 16);
        u32p[(base >> 1) + 1]        = h2 | (h3 << 16);
        u32p[((HPLW + base) >> 1)]     = l0 | (l1 << 16);
        u32p[((HPLW + base) >> 1) + 1] = l2 | (l3 << 16);
    }

    // -------- phases 1-2: 5 layers, wave-private --------
    #pragma unroll 1
    for (int L = 0; L < 5; ++L) {
        const unsigned short* wb;
        int loOff, KT;
        const float* bias;
        if (L == 0) { wb = wq;                      loOff = 8192;  KT = 2; bias = b_in; }
        else {
            wb = wq + 16384 + (L - 1) * 32768;      loOff = 16384; KT = 4;
            bias = (L == 1) ? bs0 : (L == 2) ? bs1 : (L == 3) ? bs2 : bs3;
        }

        s16x8 ah[4], al[4];
        #pragma unroll
        for (int kk = 0; kk < 4; ++kk) {
            if (kk < KT) {
                const short* ap = &hi_sh[lL * HSTR + kk * 32 + lH * 8];
                ah[kk] = *(const s16x8*)ap;
                al[kk] = *(const s16x8*)&lo_sh[lL * HSTR + kk * 32 + lH * 8];
            }
        }

        f32x4 acc[8];
        #pragma unroll
        for (int n = 0; n < 8; ++n) {
            f32x4 d = {0.f, 0.f, 0.f, 0.f};
            #pragma unroll
            for (int kk = 0; kk < 4; ++kk) {
                if (kk < KT) {
                    const unsigned short* bp_ = wb + ((n * KT + kk) * 64 + lane) * 8;
                    s16x8 bh = *(const s16x8*)bp_;
                    s16x8 bl = *(const s16x8*)(bp_ + loOff);
                    d = MFMA(ah[kk], bh, d);
                    d = MFMA(ah[kk], bl, d);
                    d = MFMA(al[kk], bh, d);
                }
            }
            acc[n] = d;
        }

        // writeback: silu(+skip) -> direct b16 stores
        #pragma unroll
        for (int n = 0; n < 8; ++n) {
            const int colb = n * 16 + lL;
            const float bv = bias[colb];
            #pragma unroll
            for (int r = 0; r < 4; ++r) {
                const int row = lH * 4 + r;
                float v = acc[n][r] + bv;
                float hnew;
                if (L > 0) {
                    float ho = bf16re(hi_sh[row * HSTR + colb]) + bf16re(lo_sh[row * HSTR + colb]);
                    hnew = silu_f(v) + ho;
                } else {
                    hnew = silu_f(v);
                }
                unsigned hi, lo; bf16split(hnew, hi, lo);
                hi_sh[row * HSTR + colb] = (short)hi;
                lo_sh[row * HSTR + colb] = (short)lo;
            }
        }
        __builtin_amdgcn_s_barrier();   // re-converge waves for L1 B-tile reuse
    }

    // -------- phase 3 + spline: wave-private, swizzled cbuf overlays arena --------
    s16x8 ah[4], al[4];
    #pragma unroll
    for (int kk = 0; kk < 4; ++kk) {
        ah[kk] = *(const s16x8*)&hi_sh[lL * HSTR + kk * 32 + lH * 8];
        al[kk] = *(const s16x8*)&lo_sh[lL * HSTR + kk * 32 + lH * 8];
    }

    const unsigned short* wop = wq + 147456;
    #pragma unroll 1
    for (int g = 0; g < 6; ++g) {
        #pragma unroll 2
        for (int nt10 = 0; nt10 < 10; ++nt10) {
            const int nt = g * 10 + nt10;
            f32x4 d = {0.f, 0.f, 0.f, 0.f};
            #pragma unroll
            for (int kk = 0; kk < 4; ++kk) {
                const unsigned short* bp_ = wop + ((nt * 4 + kk) * 64 + lane) * 8;
                s16x8 bh = *(const s16x8*)bp_;
                s16x8 bl = *(const s16x8*)(bp_ + 122880);
                d = MFMA(ah[kk], bh, d);
                d = MFMA(ah[kk], bl, d);
                d = MFMA(al[kk], bh, d);
            }
            const float bv = b_out[nt * 16 + lL];
            #pragma unroll
            for (int r = 0; r < 4; ++r) {
                const int row = lH * 4 + r;
                const int ci = row * CSTRW + nt10 * 16 + lL;
                cbufw[ci ^ ((row & 7) << 2)] = d[r] + bv;
            }
        }
        {
            const int r  = lane & 15;
            const int lg = lane >> 4;
            float ccr[40];
            #pragma unroll
            for (int j = 0; j < 40; ++j) {
                const int ci = r * CSTRW + lg * 40 + j;
                ccr[j] = cbufw[ci ^ ((r & 7) << 2)];
            }
            const size_t oi = (size_t)(r0 + r) * LEAD + g * 4 + lg;
            float ff = f[oi];
            out[oi] = spline_eval(ccr, ff);
        }
        __builtin_amdgcn_s_barrier();   // re-converge for next g's B-tiles
    }
}

// ---------------- small-ws fallback: fully fused, x input ----------------
__device__ __forceinline__ void legacy_mlp(
    const float* __restrict__ x, const float* __restrict__ p,
    const float* __restrict__ b_in,
    const float* __restrict__ bs0, const float* __restrict__ bs1,
    const float* __restrict__ bs2, const float* __restrict__ bs3,
    const unsigned short* __restrict__ wq,
    short* hpl, int t, int lane, int w, int lL, int lH, int b0)
{
    {
        const int grp = lane >> 4, sub = lane & 15;
        for (int it = 0; it < (TB * LEAD) / 16; ++it) {
            int rowl = it * 16 + w * 4 + grp;
            int D   = (b0 * LEAD + rowl) * MEM;
            int C0  = D >> 2, o0 = D & 3;
            int basei = 4 * sub - o0;
            float s = 0.f, ss = 0.f;
            if (basei < 51) {
                f32x4 v = *(const f32x4*)(x + 4 * (C0 + sub));
                #pragma unroll
                for (int i = 0; i < 4; ++i) {
                    bool ok = (basei + i >= 0) && (basei + i < 51);
                    float u = ok ? v[i] : 0.0f;
                    s += u; ss += u * u;
                }
            }
            s += __shfl_xor(s, 1);  ss += __shfl_xor(ss, 1);
            s += __shfl_xor(s, 2);  ss += __shfl_xor(ss, 2);
            s += __shfl_xor(s, 4);  ss += __shfl_xor(ss, 4);
            s += __shfl_xor(s, 8);  ss += __shfl_xor(ss, 8);
            if (sub == 0) {
                int bl = rowl / LEAD, ld = rowl - bl * LEAD;
                float mv = s / 51.0f;
                float sd = sqrtf(fmaxf((ss - 51.0f * mv * mv) / 50.0f, 0.0f));
                unsigned hi, lo;
                bf16split(mv, hi, lo);
                hpl[bl * HSTR + 2 * ld] = (short)hi;  hpl[HPL + bl * HSTR + 2 * ld] = (short)lo;
                bf16split(sd, hi, lo);
                hpl[bl * HSTR + 2 * ld + 1] = (short)hi;  hpl[HPL + bl * HSTR + 2 * ld + 1] = (short)lo;
            }
        }
        for (int idx = t; idx < TB * NPRED; idx += 256) {
            int bl = idx / NPRED, j = idx - bl * NPRED;
            unsigned hi, lo;
            bf16split(p[(size_t)(b0 + bl) * NPRED + j], hi, lo);
            hpl[bl * HSTR + 48 + j] = (short)hi;  hpl[HPL + bl * HSTR + 48 + j] = (short)lo;
        }
        {
            int row = t >> 2;
            unsigned* u32p = (unsigned*)hpl;
            for (int c2 = 54 + 2 * (t & 3); c2 < 64; c2 += 8) {
                u32p[(row * HSTR + c2) >> 1] = 0u;
                u32p[(HPL + row * HSTR + c2) >> 1] = 0u;
            }
        }
    }
    __syncthreads();

    #pragma unroll 1
    for (int L = 0; L < 5; ++L) {
        const unsigned short* wb; int loOff, KT; const float* bias;
        if (L == 0) { wb = wq; loOff = 8192; KT = 2; bias = b_in; }
        else {
            wb = wq + 16384 + (L - 1) * 32768; loOff = 16384; KT = 4;
            bias = (L == 1) ? bs0 : (L == 2) ? bs1 : (L == 3) ? bs2 : bs3;
        }
        f32x4 acc[4][2];
        #pragma unroll
        for (int m = 0; m < 4; ++m)
            #pragma unroll
            for (int n = 0; n < 2; ++n) acc[m][n] = (f32x4){0.f, 0.f, 0.f, 0.f};
        #pragma unroll
        for (int n = 0; n < 2; ++n) {
            const int tile = w * 2 + n;
            #pragma unroll
            for (int kk = 0; kk < 4; ++kk) {
                if (kk < KT) {
                    const unsigned short* bp_ = wb + ((tile * KT + kk) * 64 + lane) * 8;
                    s16x8 bh = *(const s16x8*)bp_;
                    s16x8 bl = *(const s16x8*)(bp_ + loOff);
                    #pragma unroll
                    for (int m = 0; m < 4; ++m) {
                        const short* ap = &hpl[(m * 16 + lL) * HSTR + kk * 32 + lH * 8];
                        s16x8 ah = *(const s16x8*)ap;
                        s16x8 al = *(const s16x8*)(ap + HPL);
                        acc[m][n] = MFMA(ah, bh, acc[m][n]);
                        acc[m][n] = MFMA(ah, bl, acc[m][n]);
                        acc[m][n] = MFMA(al, bh, acc[m][n]);
                    }
                }
            }
        }
        __syncthreads();
        #pragma unroll
        for (int n = 0; n < 2; ++n) {
            const int colb = w * 32 + n * 16 + lL;
            const float bv = bias[colb];
            #pragma unroll
            for (int m = 0; m < 4; ++m) {
                #pragma unroll
                for (int r = 0; r < 4; ++r) {
                    const int row = m * 16 + lH * 4 + r;
                    float v = acc[m][n][r] + bv;
                    float hnew;
                    if (L > 0) {
                        float ho = bf16re(hpl[row * HSTR + colb]) + bf16re(hpl[HPL + row * HSTR + colb]);
                        hnew = silu_f(v) + ho;
                    } else {
                        hnew = silu_f(v);
                    }
                    unsigned hi, lo; bf16split(hnew, hi, lo);
                    hpl[row * HSTR + colb]       = (short)hi;
                    hpl[HPL + row * HSTR + colb] = (short)lo;
                }
            }
        }
        __syncthreads();
    }
}

__global__ __launch_bounds__(256, 2) void fused_mfma_kernel(
    const float* __restrict__ x, const float* __restrict__ p, const float* __restrict__ f,
    const float* __restrict__ b_in,
    const float* __restrict__ bs0, const float* __restrict__ bs1,
    const float* __restrict__ bs2, const float* __restrict__ bs3,
    const float* __restrict__ b_out,
    const unsigned short* __restrict__ wq,
    float* __restrict__ out)
{
    __shared__ short hpl[2 * HPL];
    __shared__ float cbuf[64 * CSTR];

    const int t    = threadIdx.x;
    const int lane = t & 63;
    const int w    = t >> 6;
    const int lL   = lane & 15;
    const int lH   = lane >> 4;
    const int b0   = blockIdx.x * TB;

    legacy_mlp(x, p, b_in, bs0, bs1, bs2, bs3, wq, hpl, t, lane, w, lL, lH, b0);

    const unsigned short* wop = wq + 147456;
    #pragma unroll 1
    for (int g = 0; g < 6; ++g) {
        #pragma unroll 1
        for (int nt = 0; nt < 10; ++nt) {
            const int colg = g * 160 + nt * 16 + lL;
            f32x4 d = {0.f, 0.f, 0.f, 0.f};
            #pragma unroll
            for (int kk = 0; kk < 4; ++kk) {
                const unsigned short* bp_ = wop + (((g * 10 + nt) * 4 + kk) * 64 + lane) * 8;
                s16x8 bh = *(const s16x8*)bp_;
                s16x8 bl = *(const s16x8*)(bp_ + 122880);
                const short* ap = &hpl[(w * 16 + lL) * HSTR + kk * 32 + lH * 8];
                s16x8 ah = *(const s16x8*)ap;
                s16x8 al = *(const s16x8*)(ap + HPL);
                d = MFMA(ah, bh, d);
                d = MFMA(ah, bl, d);
                d = MFMA(al, bh, d);
            }
            const float bv = b_out[colg];
            #pragma unroll
            for (int r = 0; r < 4; ++r)
                cbuf[(w * 16 + lH * 4 + r) * CSTR + nt * 16 + lL] = d[r] + bv;
        }
        __syncthreads();
        {
            const int b = t & 63, l = t >> 6;
            const float* cc = &cbuf[b * CSTR + l * 40];
            float ff = f[(size_t)(b0 + b) * LEAD + g * 4 + l];
            out[(size_t)(b0 + b) * LEAD + g * 4 + l] = spline_eval(cc, ff);
        }
        __syncthreads();
    }
}

extern "C" void kernel_launch(void* const* d_in, const int* in_sizes, int n_in,
                              void* d_out, int out_size, void* d_ws, size_t ws_size,
                              hipStream_t stream) {
    const float* x     = (const float*)d_in[0];
    const float* p     = (const float*)d_in[1];
    const float* f     = (const float*)d_in[2];
    const float* W_in  = (const float*)d_in[3];
    const float* b_in  = (const float*)d_in[4];
    const float* Ws0   = (const float*)d_in[5];
    const float* bs0   = (const float*)d_in[6];
    const float* Ws1   = (const float*)d_in[7];
    const float* bs1   = (const float*)d_in[8];
    const float* Ws2   = (const float*)d_in[9];
    const float* bs2   = (const float*)d_in[10];
    const float* Ws3   = (const float*)d_in[11];
    const float* bs3   = (const float*)d_in[12];
    const float* W_out = (const float*)d_in[13];
    const float* b_out = (const float*)d_in[14];
    float* out = (float*)d_out;

    unsigned short* wq = (unsigned short*)d_ws;
    float* feat = (float*)((char*)d_ws + WS_BYTES);

    if (ws_size >= WS_FUSED) {
        prep_kernel<<<768, 256, 0, stream>>>(W_in, Ws0, Ws1, Ws2, Ws3, W_out, wq);
        stats_kernel<<<2048, 256, 0, stream>>>(x, p, feat);
        fused_wave_kernel<<<BATCH / TB, 256, 0, stream>>>(
            feat, f, b_in, bs0, bs1, bs2, bs3, b_out, wq, out);
    } else if (ws_size >= (size_t)WS_BYTES) {
        prep_kernel<<<768, 256, 0, stream>>>(W_in, Ws0, Ws1, Ws2, Ws3, W_out, wq);
        fused_mfma_kernel<<<BATCH / TB, 256, 0, stream>>>(
            x, p, f, b_in, bs0, bs1, bs2, bs3, b_out, wq, out);
    }
}

// Round 24
// 282.617 us; speedup vs baseline: 1.0364x; 1.0364x over previous
//
#include <hip/hip_runtime.h>
#include <math.h>

#define BATCH 65536
#define LEAD  24
#define MEM   51
#define NPRED 6
#define HID   128
#define TB    64
#define NBLK  4
#define OUTC  960
#define XTOTF (BATCH * LEAD * MEM)

#define HSTR  136                 // bf16 plane row stride (shorts)
#define HPLW  (16 * HSTR)         // shorts per wave-plane (16 rows)
#define CSTRW 160                 // wave-kernel cbuf stride; 4 arenas = 40960 B -> 4 blocks/CU
#define ARENA_B (16 * CSTRW * 4)  // 10240 B
#define CSTR  165                 // legacy fallback cbuf stride
#define HPL   (64 * HSTR)         // legacy fallback plane size
// d_ws: [0, 786432) weights (frag-major) | [+FEAT_BYTES) feat f32 [BATCH][64]
#define WS_BYTES   786432
#define FEAT_BYTES ((size_t)BATCH * 64 * 4)
#define WS_FUSED   ((size_t)WS_BYTES + FEAT_BYTES)

typedef float f32x4 __attribute__((ext_vector_type(4)));
typedef short s16x8 __attribute__((ext_vector_type(8)));

// Fast-math forms (v_exp/v_log/v_rcp): rel err ~1e-6/op; absmax headroom is 8x.
__device__ __forceinline__ float sp_softplus(float z) {
    return fmaxf(z, 0.0f) + __logf(1.0f + __expf(-fabsf(z)));
}
__device__ __forceinline__ float silu_f(float z) {
    return __fdividef(z, 1.0f + __expf(-z));
}
__device__ __forceinline__ void bf16split(float x, unsigned &hi, unsigned &lo) {
    unsigned xb = __float_as_uint(x);
    hi = xb >> 16;
    float fhi = __uint_as_float(xb & 0xFFFF0000u);
    lo = __float_as_uint(x - fhi) >> 16;
}
__device__ __forceinline__ float bf16re(short u) {
    return __uint_as_float(((unsigned)(unsigned short)u) << 16);
}

// ---------------- prep: transpose + hi/lo split, fragment-major ----------------
__global__ __launch_bounds__(256) void prep_kernel(
    const float* __restrict__ W_in,
    const float* __restrict__ Ws0, const float* __restrict__ Ws1,
    const float* __restrict__ Ws2, const float* __restrict__ Ws3,
    const float* __restrict__ W_out, unsigned short* __restrict__ wq)
{
    int idx = blockIdx.x * 256 + threadIdx.x;
    float val; int ih, il;
    if (idx < 8192) {                  // W_inT: tile(8) x kt(2) x lane x j
        int tile = idx >> 10, rem = idx & 1023;
        int kk = rem >> 9, lane = (rem >> 3) & 63, j = rem & 7;
        int col = tile * 16 + (lane & 15);
        int k   = kk * 32 + (lane >> 4) * 8 + j;
        val = (k < 54) ? W_in[k * HID + col] : 0.0f;
        ih = idx; il = 8192 + idx;
    } else if (idx < 73728) {          // WsT: 4 layers x tile(8) x kt(4)
        int r = idx - 8192, l = r >> 14, r2 = r & 16383;
        int tile = r2 >> 11, rem = r2 & 2047;
        int kk = rem >> 9, lane = (rem >> 3) & 63, j = rem & 7;
        int col = tile * 16 + (lane & 15);
        int k   = kk * 32 + (lane >> 4) * 8 + j;
        const float* W = (l == 0) ? Ws0 : (l == 1) ? Ws1 : (l == 2) ? Ws2 : Ws3;
        val = W[k * HID + col];
        ih = 16384 + l * 32768 + r2; il = ih + 16384;
    } else {                           // W_outT: tile(60) x kt(4)
        int r = idx - 73728;
        int tile = r >> 11, rem = r & 2047;
        int kk = rem >> 9, lane = (rem >> 3) & 63, j = rem & 7;
        int col = tile * 16 + (lane & 15);
        int k   = kk * 32 + (lane >> 4) * 8 + j;
        val = W_out[k * OUTC + col];
        ih = 147456 + r; il = 270336 + r;
    }
    unsigned hi, lo; bf16split(val, hi, lo);
    wq[ih] = (unsigned short)hi;
    wq[il] = (unsigned short)lo;
}

// ---------------- stats: pure-BW kernel, x -> feat[BATCH][64] (full precision) ----------------
__global__ __launch_bounds__(256, 8) void stats_kernel(
    const float* __restrict__ x, const float* __restrict__ p,
    float* __restrict__ feat)
{
    const int t   = threadIdx.x;
    const int sub = t & 15;
    const int g0  = blockIdx.x * 16 + (t >> 4);
    const int NG  = gridDim.x * 16;
    for (int row = g0; row < BATCH * LEAD; row += NG) {
        int D  = row * MEM;
        int C0 = D >> 2, o0 = D & 3;
        int basei = 4 * sub - o0;
        float s = 0.f, ss = 0.f;
        if (basei < 51) {
            int ci = C0 + sub;
            if (4 * ci + 4 <= XTOTF) {
                f32x4 v = *(const f32x4*)(x + 4 * ci);
                #pragma unroll
                for (int i = 0; i < 4; ++i) {
                    bool ok = (basei + i >= 0) && (basei + i < 51);
                    float u = ok ? v[i] : 0.0f;
                    s += u; ss += u * u;
                }
            } else {
                #pragma unroll
                for (int i = 0; i < 4; ++i) {
                    int gi = 4 * ci + i;
                    bool ok = (basei + i >= 0) && (basei + i < 51) && (gi < XTOTF);
                    float u = ok ? x[gi] : 0.0f;
                    s += u; ss += u * u;
                }
            }
        }
        s += __shfl_xor(s, 1);  ss += __shfl_xor(ss, 1);
        s += __shfl_xor(s, 2);  ss += __shfl_xor(ss, 2);
        s += __shfl_xor(s, 4);  ss += __shfl_xor(ss, 4);
        s += __shfl_xor(s, 8);  ss += __shfl_xor(ss, 8);
        if (sub == 0) {
            int b = row / LEAD, ld = row - b * LEAD;
            float mv = s / 51.0f;
            float sd = sqrtf(fmaxf((ss - 51.0f * mv * mv) / 50.0f, 0.0f));
            float* fr = feat + (size_t)b * 64;
            fr[2 * ld]     = mv;
            fr[2 * ld + 1] = sd;
        }
    }
    for (size_t idx = (size_t)blockIdx.x * 256 + t; idx < (size_t)BATCH * 16;
         idx += (size_t)gridDim.x * 256) {
        int b = (int)(idx >> 4), c = (int)(idx & 15) + 48;
        feat[(size_t)b * 64 + c] = (c < 54) ? p[(size_t)b * NPRED + (c - 48)] : 0.0f;
    }
}

#define MFMA(a, b, c) __builtin_amdgcn_mfma_f32_16x16x32_bf16((a), (b), (c), 0, 0, 0)

// ---------------- spline body (fast-math; cc may be a register array) ----------------
__device__ __forceinline__ float spline_eval(const float* cc, float ff) {
    float dt_prod = 1.0f;
    #pragma unroll
    for (int blk = 0; blk < NBLK; ++blk) {
        float tk[5], yk[5];
        tk[0] = cc[blk * 10 + 0];
        yk[0] = cc[blk * 10 + 5];
        #pragma unroll
        for (int kk = 1; kk < 5; ++kk) {
            tk[kk] = tk[kk - 1] + 0.001f + sp_softplus(cc[blk * 10 + kk]);
            yk[kk] = yk[kk - 1] + 0.001f + sp_softplus(cc[blk * 10 + 5 + kk]);
        }
        float df[4];
        #pragma unroll
        for (int j = 0; j < 4; ++j) df[j] = __fdividef(yk[j + 1] - yk[j], tk[j + 1] - tk[j]);
        float g02 = __fdividef(yk[2] - yk[0], tk[2] - tk[0]);
        float g13 = __fdividef(yk[3] - yk[1], tk[3] - tk[1]);
        float g24 = __fdividef(yk[4] - yk[2], tk[4] - tk[2]);
        float dd[5];
        dd[0] = __fdividef(df[0] * df[0], g02);
        dd[1] = __fdividef(df[0] * df[1], g02);
        dd[2] = __fdividef(df[1] * df[2], g13);
        dd[3] = __fdividef(df[2] * df[3], g24);
        dd[4] = __fdividef(df[3] * df[3], g24);

        int cnt = (ff > tk[0]) + (ff > tk[1]) + (ff > tk[2]) + (ff > tk[3]) + (ff > tk[4]);
        bool e0 = (cnt == 0), e1 = (cnt == 5);
        int k0 = cnt - 1; k0 = k0 < 0 ? 0 : (k0 > 3 ? 3 : k0);

        float t0v = tk[0], t1v = tk[1], y0v = yk[0], y1v = yk[1], d0v = dd[0], d1v = dd[1];
        #pragma unroll
        for (int j = 1; j < 4; ++j) {
            bool c = (k0 == j);
            t0v = c ? tk[j] : t0v;  t1v = c ? tk[j + 1] : t1v;
            y0v = c ? yk[j] : y0v;  y1v = c ? yk[j + 1] : y1v;
            d0v = c ? dd[j] : d0v;  d1v = c ? dd[j + 1] : d1v;
        }

        float dt_ = t1v - t0v, dy_ = y1v - y0v;
        float s_  = __fdividef(dy_, dt_);
        float e   = __fdividef(ff - t0v, dt_);
        float one_e = 1.0f - e;
        float bb  = d1v + d0v - 2.0f * s_;
        float n0  = dy_ * (s_ * e * e + d0v * e * one_e);
        float n1  = s_ + bb * e * one_e;
        float p_mid = y0v + __fdividef(n0, n1);
        float p_lo  = d0v * ff + (y0v - d0v * t0v);
        float p_hi  = d1v * ff + (y1v - d1v * t1v);
        float val = e0 ? p_lo : (e1 ? p_hi : p_mid);

        float div0 = s_ * s_ * (d1v * e * e + 2.0f * s_ * e * one_e + d0v * one_e * one_e);
        float div1 = n1 * n1;
        float der  = e0 ? d0v : (e1 ? d1v : __fdividef(div0, div1));

        dt_prod *= der;
        ff = val;
    }
    return __expf(-0.5f * ff * ff) * dt_prod * 0.3989422804014327f;  // 1/sqrt(2pi)
}

// ---------------- barrier-free fused kernel: wave-private 16-row pipeline ----------------
// cbuf XOR-swizzle: dword idx ^= (row&7)<<2 -> spline reads 16-way -> 2-way.
// NO barriers anywhere (round 23 showed s_barrier re-convoying costs ~20%).
__global__ __launch_bounds__(256, 2) void fused_wave_kernel(
    const float* __restrict__ feat, const float* __restrict__ f,
    const float* __restrict__ b_in,
    const float* __restrict__ bs0, const float* __restrict__ bs1,
    const float* __restrict__ bs2, const float* __restrict__ bs3,
    const float* __restrict__ b_out,
    const unsigned short* __restrict__ wq,
    float* __restrict__ out)
{
    __shared__ __align__(16) char smem[4 * ARENA_B];

    const int t    = threadIdx.x;
    const int lane = t & 63;
    const int w    = t >> 6;
    const int lL   = lane & 15;
    const int lH   = lane >> 4;
    const int b0   = blockIdx.x * TB;
    const int r0   = b0 + w * 16;          // this wave's first global row

    short* hi_sh = (short*)(smem + w * ARENA_B);
    short* lo_sh = hi_sh + HPLW;
    float* cbufw = (float*)(smem + w * ARENA_B);
    unsigned* u32p = (unsigned*)hi_sh;

    // -------- phase 0': feat -> wave-private split-bf16 planes --------
    #pragma unroll
    for (int i = 0; i < 4; ++i) {
        int idx = i * 64 + lane;            // 0..255 : 16 rows x 16 chunks
        int r  = idx >> 4, c4 = (idx & 15) * 4;
        f32x4 v = *(const f32x4*)(feat + (size_t)(r0 + r) * 64 + c4);
        unsigned h0, l0, h1, l1, h2, l2, h3, l3;
        bf16split(v[0], h0, l0); bf16split(v[1], h1, l1);
        bf16split(v[2], h2, l2); bf16split(v[3], h3, l3);
        int base = r * HSTR + c4;           // even
        u32p[(base >> 1)]            = h0 | (h1 << 16);
        u32p[(base >> 1) + 1]        = h2 | (h3 << 16);
        u32p[((HPLW + base) >> 1)]     = l0 | (l1 << 16);
        u32p[((HPLW + base) >> 1) + 1] = l2 | (l3 << 16);
    }

    // -------- phases 1-2: 5 layers, wave-private --------
    #pragma unroll 1
    for (int L = 0; L < 5; ++L) {
        const unsigned short* wb;
        int loOff, KT;
        const float* bias;
        if (L == 0) { wb = wq;                      loOff = 8192;  KT = 2; bias = b_in; }
        else {
            wb = wq + 16384 + (L - 1) * 32768;      loOff = 16384; KT = 4;
            bias = (L == 1) ? bs0 : (L == 2) ? bs1 : (L == 3) ? bs2 : bs3;
        }

        s16x8 ah[4], al[4];
        #pragma unroll
        for (int kk = 0; kk < 4; ++kk) {
            if (kk < KT) {
                const short* ap = &hi_sh[lL * HSTR + kk * 32 + lH * 8];
                ah[kk] = *(const s16x8*)ap;
                al[kk] = *(const s16x8*)&lo_sh[lL * HSTR + kk * 32 + lH * 8];
            }
        }

        f32x4 acc[8];
        #pragma unroll
        for (int n = 0; n < 8; ++n) {
            f32x4 d = {0.f, 0.f, 0.f, 0.f};
            #pragma unroll
            for (int kk = 0; kk < 4; ++kk) {
                if (kk < KT) {
                    const unsigned short* bp_ = wb + ((n * KT + kk) * 64 + lane) * 8;
                    s16x8 bh = *(const s16x8*)bp_;
                    s16x8 bl = *(const s16x8*)(bp_ + loOff);
                    d = MFMA(ah[kk], bh, d);
                    d = MFMA(ah[kk], bl, d);
                    d = MFMA(al[kk], bh, d);
                }
            }
            acc[n] = d;
        }

        // writeback: silu(+skip) -> direct b16 stores
        #pragma unroll
        for (int n = 0; n < 8; ++n) {
            const int colb = n * 16 + lL;
            const float bv = bias[colb];
            #pragma unroll
            for (int r = 0; r < 4; ++r) {
                const int row = lH * 4 + r;
                float v = acc[n][r] + bv;
                float hnew;
                if (L > 0) {
                    float ho = bf16re(hi_sh[row * HSTR + colb]) + bf16re(lo_sh[row * HSTR + colb]);
                    hnew = silu_f(v) + ho;
                } else {
                    hnew = silu_f(v);
                }
                unsigned hi, lo; bf16split(hnew, hi, lo);
                hi_sh[row * HSTR + colb] = (short)hi;
                lo_sh[row * HSTR + colb] = (short)lo;
            }
        }
    }

    // -------- phase 3 + spline: wave-private, swizzled cbuf overlays arena --------
    s16x8 ah[4], al[4];
    #pragma unroll
    for (int kk = 0; kk < 4; ++kk) {
        ah[kk] = *(const s16x8*)&hi_sh[lL * HSTR + kk * 32 + lH * 8];
        al[kk] = *(const s16x8*)&lo_sh[lL * HSTR + kk * 32 + lH * 8];
    }

    const unsigned short* wop = wq + 147456;
    #pragma unroll 1
    for (int g = 0; g < 6; ++g) {
        #pragma unroll 2
        for (int nt10 = 0; nt10 < 10; ++nt10) {
            const int nt = g * 10 + nt10;
            f32x4 d = {0.f, 0.f, 0.f, 0.f};
            #pragma unroll
            for (int kk = 0; kk < 4; ++kk) {
                const unsigned short* bp_ = wop + ((nt * 4 + kk) * 64 + lane) * 8;
                s16x8 bh = *(const s16x8*)bp_;
                s16x8 bl = *(const s16x8*)(bp_ + 122880);
                d = MFMA(ah[kk], bh, d);
                d = MFMA(ah[kk], bl, d);
                d = MFMA(al[kk], bh, d);
            }
            const float bv = b_out[nt * 16 + lL];
            #pragma unroll
            for (int r = 0; r < 4; ++r) {
                const int row = lH * 4 + r;
                const int ci = row * CSTRW + nt10 * 16 + lL;
                cbufw[ci ^ ((row & 7) << 2)] = d[r] + bv;
            }
        }
        {
            const int r  = lane & 15;
            const int lg = lane >> 4;
            float ccr[40];
            #pragma unroll
            for (int j = 0; j < 40; ++j) {
                const int ci = r * CSTRW + lg * 40 + j;
                ccr[j] = cbufw[ci ^ ((r & 7) << 2)];
            }
            const size_t oi = (size_t)(r0 + r) * LEAD + g * 4 + lg;
            float ff = f[oi];
            out[oi] = spline_eval(ccr, ff);
        }
    }
}

// ---------------- small-ws fallback: fully fused, x input ----------------
__device__ __forceinline__ void legacy_mlp(
    const float* __restrict__ x, const float* __restrict__ p,
    const float* __restrict__ b_in,
    const float* __restrict__ bs0, const float* __restrict__ bs1,
    const float* __restrict__ bs2, const float* __restrict__ bs3,
    const unsigned short* __restrict__ wq,
    short* hpl, int t, int lane, int w, int lL, int lH, int b0)
{
    {
        const int grp = lane >> 4, sub = lane & 15;
        for (int it = 0; it < (TB * LEAD) / 16; ++it) {
            int rowl = it * 16 + w * 4 + grp;
            int D   = (b0 * LEAD + rowl) * MEM;
            int C0  = D >> 2, o0 = D & 3;
            int basei = 4 * sub - o0;
            float s = 0.f, ss = 0.f;
            if (basei < 51) {
                f32x4 v = *(const f32x4*)(x + 4 * (C0 + sub));
                #pragma unroll
                for (int i = 0; i < 4; ++i) {
                    bool ok = (basei + i >= 0) && (basei + i < 51);
                    float u = ok ? v[i] : 0.0f;
                    s += u; ss += u * u;
                }
            }
            s += __shfl_xor(s, 1);  ss += __shfl_xor(ss, 1);
            s += __shfl_xor(s, 2);  ss += __shfl_xor(ss, 2);
            s += __shfl_xor(s, 4);  ss += __shfl_xor(ss, 4);
            s += __shfl_xor(s, 8);  ss += __shfl_xor(ss, 8);
            if (sub == 0) {
                int bl = rowl / LEAD, ld = rowl - bl * LEAD;
                float mv = s / 51.0f;
                float sd = sqrtf(fmaxf((ss - 51.0f * mv * mv) / 50.0f, 0.0f));
                unsigned hi, lo;
                bf16split(mv, hi, lo);
                hpl[bl * HSTR + 2 * ld] = (short)hi;  hpl[HPL + bl * HSTR + 2 * ld] = (short)lo;
                bf16split(sd, hi, lo);
                hpl[bl * HSTR + 2 * ld + 1] = (short)hi;  hpl[HPL + bl * HSTR + 2 * ld + 1] = (short)lo;
            }
        }
        for (int idx = t; idx < TB * NPRED; idx += 256) {
            int bl = idx / NPRED, j = idx - bl * NPRED;
            unsigned hi, lo;
            bf16split(p[(size_t)(b0 + bl) * NPRED + j], hi, lo);
            hpl[bl * HSTR + 48 + j] = (short)hi;  hpl[HPL + bl * HSTR + 48 + j] = (short)lo;
        }
        {
            int row = t >> 2;
            unsigned* u32p = (unsigned*)hpl;
            for (int c2 = 54 + 2 * (t & 3); c2 < 64; c2 += 8) {
                u32p[(row * HSTR + c2) >> 1] = 0u;
                u32p[(HPL + row * HSTR + c2) >> 1] = 0u;
            }
        }
    }
    __syncthreads();

    #pragma unroll 1
    for (int L = 0; L < 5; ++L) {
        const unsigned short* wb; int loOff, KT; const float* bias;
        if (L == 0) { wb = wq; loOff = 8192; KT = 2; bias = b_in; }
        else {
            wb = wq + 16384 + (L - 1) * 32768; loOff = 16384; KT = 4;
            bias = (L == 1) ? bs0 : (L == 2) ? bs1 : (L == 3) ? bs2 : bs3;
        }
        f32x4 acc[4][2];
        #pragma unroll
        for (int m = 0; m < 4; ++m)
            #pragma unroll
            for (int n = 0; n < 2; ++n) acc[m][n] = (f32x4){0.f, 0.f, 0.f, 0.f};
        #pragma unroll
        for (int n = 0; n < 2; ++n) {
            const int tile = w * 2 + n;
            #pragma unroll
            for (int kk = 0; kk < 4; ++kk) {
                if (kk < KT) {
                    const unsigned short* bp_ = wb + ((tile * KT + kk) * 64 + lane) * 8;
                    s16x8 bh = *(const s16x8*)bp_;
                    s16x8 bl = *(const s16x8*)(bp_ + loOff);
                    #pragma unroll
                    for (int m = 0; m < 4; ++m) {
                        const short* ap = &hpl[(m * 16 + lL) * HSTR + kk * 32 + lH * 8];
                        s16x8 ah = *(const s16x8*)ap;
                        s16x8 al = *(const s16x8*)(ap + HPL);
                        acc[m][n] = MFMA(ah, bh, acc[m][n]);
                        acc[m][n] = MFMA(ah, bl, acc[m][n]);
                        acc[m][n] = MFMA(al, bh, acc[m][n]);
                    }
                }
            }
        }
        __syncthreads();
        #pragma unroll
        for (int n = 0; n < 2; ++n) {
            const int colb = w * 32 + n * 16 + lL;
            const float bv = bias[colb];
            #pragma unroll
            for (int m = 0; m < 4; ++m) {
                #pragma unroll
                for (int r = 0; r < 4; ++r) {
                    const int row = m * 16 + lH * 4 + r;
                    float v = acc[m][n][r] + bv;
                    float hnew;
                    if (L > 0) {
                        float ho = bf16re(hpl[row * HSTR + colb]) + bf16re(hpl[HPL + row * HSTR + colb]);
                        hnew = silu_f(v) + ho;
                    } else {
                        hnew = silu_f(v);
                    }
                    unsigned hi, lo; bf16split(hnew, hi, lo);
                    hpl[row * HSTR + colb]       = (short)hi;
                    hpl[HPL + row * HSTR + colb] = (short)lo;
                }
            }
        }
        __syncthreads();
    }
}

__global__ __launch_bounds__(256, 2) void fused_mfma_kernel(
    const float* __restrict__ x, const float* __restrict__ p, const float* __restrict__ f,
    const float* __restrict__ b_in,
    const float* __restrict__ bs0, const float* __restrict__ bs1,
    const float* __restrict__ bs2, const float* __restrict__ bs3,
    const float* __restrict__ b_out,
    const unsigned short* __restrict__ wq,
    float* __restrict__ out)
{
    __shared__ short hpl[2 * HPL];
    __shared__ float cbuf[64 * CSTR];

    const int t    = threadIdx.x;
    const int lane = t & 63;
    const int w    = t >> 6;
    const int lL   = lane & 15;
    const int lH   = lane >> 4;
    const int b0   = blockIdx.x * TB;

    legacy_mlp(x, p, b_in, bs0, bs1, bs2, bs3, wq, hpl, t, lane, w, lL, lH, b0);

    const unsigned short* wop = wq + 147456;
    #pragma unroll 1
    for (int g = 0; g < 6; ++g) {
        #pragma unroll 1
        for (int nt = 0; nt < 10; ++nt) {
            const int colg = g * 160 + nt * 16 + lL;
            f32x4 d = {0.f, 0.f, 0.f, 0.f};
            #pragma unroll
            for (int kk = 0; kk < 4; ++kk) {
                const unsigned short* bp_ = wop + (((g * 10 + nt) * 4 + kk) * 64 + lane) * 8;
                s16x8 bh = *(const s16x8*)bp_;
                s16x8 bl = *(const s16x8*)(bp_ + 122880);
                const short* ap = &hpl[(w * 16 + lL) * HSTR + kk * 32 + lH * 8];
                s16x8 ah = *(const s16x8*)ap;
                s16x8 al = *(const s16x8*)(ap + HPL);
                d = MFMA(ah, bh, d);
                d = MFMA(ah, bl, d);
                d = MFMA(al, bh, d);
            }
            const float bv = b_out[colg];
            #pragma unroll
            for (int r = 0; r < 4; ++r)
                cbuf[(w * 16 + lH * 4 + r) * CSTR + nt * 16 + lL] = d[r] + bv;
        }
        __syncthreads();
        {
            const int b = t & 63, l = t >> 6;
            const float* cc = &cbuf[b * CSTR + l * 40];
            float ff = f[(size_t)(b0 + b) * LEAD + g * 4 + l];
            out[(size_t)(b0 + b) * LEAD + g * 4 + l] = spline_eval(cc, ff);
        }
        __syncthreads();
    }
}

extern "C" void kernel_launch(void* const* d_in, const int* in_sizes, int n_in,
                              void* d_out, int out_size, void* d_ws, size_t ws_size,
                              hipStream_t stream) {
    const float* x     = (const float*)d_in[0];
    const float* p     = (const float*)d_in[1];
    const float* f     = (const float*)d_in[2];
    const float* W_in  = (const float*)d_in[3];
    const float* b_in  = (const float*)d_in[4];
    const float* Ws0   = (const float*)d_in[5];
    const float* bs0   = (const float*)d_in[6];
    const float* Ws1   = (const float*)d_in[7];
    const float* bs1   = (const float*)d_in[8];
    const float* Ws2   = (const float*)d_in[9];
    const float* bs2   = (const float*)d_in[10];
    const float* Ws3   = (const float*)d_in[11];
    const float* bs3   = (const float*)d_in[12];
    const float* W_out = (const float*)d_in[13];
    const float* b_out = (const float*)d_in[14];
    float* out = (float*)d_out;

    unsigned short* wq = (unsigned short*)d_ws;
    float* feat = (float*)((char*)d_ws + WS_BYTES);

    if (ws_size >= WS_FUSED) {
        prep_kernel<<<768, 256, 0, stream>>>(W_in, Ws0, Ws1, Ws2, Ws3, W_out, wq);
        stats_kernel<<<2048, 256, 0, stream>>>(x, p, feat);
        fused_wave_kernel<<<BATCH / TB, 256, 0, stream>>>(
            feat, f, b_in, bs0, bs1, bs2, bs3, b_out, wq, out);
    } else if (ws_size >= (size_t)WS_BYTES) {
        prep_kernel<<<768, 256, 0, stream>>>(W_in, Ws0, Ws1, Ws2, Ws3, W_out, wq);
        fused_mfma_kernel<<<BATCH / TB, 256, 0, stream>>>(
            x, p, f, b_in, bs0, bs1, bs2, bs3, b_out, wq, out);
    }
}

// Round 25
// 242.326 us; speedup vs baseline: 1.2087x; 1.1663x over previous
//
#include <hip/hip_runtime.h>
#include <math.h>

#define BATCH 65536
#define LEAD  24
#define MEM   51
#define NPRED 6
#define HID   128
#define TB    64
#define NBLK  4
#define OUTC  960
#define XTOTF (BATCH * LEAD * MEM)

#define HSTR  136                 // bf16 plane row stride (shorts)
#define HPLW  (16 * HSTR)         // shorts per wave-plane (16 rows)
#define CSTRW 160                 // wave-kernel cbuf stride; 4 arenas = 40960 B -> 4 blocks/CU
#define ARENA_B (16 * CSTRW * 4)  // 10240 B
#define CSTR  165                 // legacy fallback cbuf stride
#define HPL   (64 * HSTR)         // legacy fallback plane size
// d_ws: [0, 786432) weights (frag-major) | [+FEAT_BYTES) feat f32 [BATCH][64]
#define WS_BYTES   786432
#define FEAT_BYTES ((size_t)BATCH * 64 * 4)
#define WS_FUSED   ((size_t)WS_BYTES + FEAT_BYTES)

typedef float f32x4 __attribute__((ext_vector_type(4)));
typedef short s16x8 __attribute__((ext_vector_type(8)));

// Fast-math forms (v_exp/v_log/v_rcp): rel err ~1e-6/op; absmax headroom is 8x.
__device__ __forceinline__ float sp_softplus(float z) {
    return fmaxf(z, 0.0f) + __logf(1.0f + __expf(-fabsf(z)));
}
__device__ __forceinline__ float silu_f(float z) {
    return __fdividef(z, 1.0f + __expf(-z));
}
__device__ __forceinline__ void bf16split(float x, unsigned &hi, unsigned &lo) {
    unsigned xb = __float_as_uint(x);
    hi = xb >> 16;
    float fhi = __uint_as_float(xb & 0xFFFF0000u);
    lo = __float_as_uint(x - fhi) >> 16;
}
__device__ __forceinline__ float bf16re(short u) {
    return __uint_as_float(((unsigned)(unsigned short)u) << 16);
}

// ---------------- prep: transpose + hi/lo split, fragment-major ----------------
__global__ __launch_bounds__(256) void prep_kernel(
    const float* __restrict__ W_in,
    const float* __restrict__ Ws0, const float* __restrict__ Ws1,
    const float* __restrict__ Ws2, const float* __restrict__ Ws3,
    const float* __restrict__ W_out, unsigned short* __restrict__ wq)
{
    int idx = blockIdx.x * 256 + threadIdx.x;
    float val; int ih, il;
    if (idx < 8192) {                  // W_inT: tile(8) x kt(2) x lane x j
        int tile = idx >> 10, rem = idx & 1023;
        int kk = rem >> 9, lane = (rem >> 3) & 63, j = rem & 7;
        int col = tile * 16 + (lane & 15);
        int k   = kk * 32 + (lane >> 4) * 8 + j;
        val = (k < 54) ? W_in[k * HID + col] : 0.0f;
        ih = idx; il = 8192 + idx;
    } else if (idx < 73728) {          // WsT: 4 layers x tile(8) x kt(4)
        int r = idx - 8192, l = r >> 14, r2 = r & 16383;
        int tile = r2 >> 11, rem = r2 & 2047;
        int kk = rem >> 9, lane = (rem >> 3) & 63, j = rem & 7;
        int col = tile * 16 + (lane & 15);
        int k   = kk * 32 + (lane >> 4) * 8 + j;
        const float* W = (l == 0) ? Ws0 : (l == 1) ? Ws1 : (l == 2) ? Ws2 : Ws3;
        val = W[k * HID + col];
        ih = 16384 + l * 32768 + r2; il = ih + 16384;
    } else {                           // W_outT: tile(60) x kt(4)
        int r = idx - 73728;
        int tile = r >> 11, rem = r & 2047;
        int kk = rem >> 9, lane = (rem >> 3) & 63, j = rem & 7;
        int col = tile * 16 + (lane & 15);
        int k   = kk * 32 + (lane >> 4) * 8 + j;
        val = W_out[k * OUTC + col];
        ih = 147456 + r; il = 270336 + r;
    }
    unsigned hi, lo; bf16split(val, hi, lo);
    wq[ih] = (unsigned short)hi;
    wq[il] = (unsigned short)lo;
}

// ---------------- stats: pure-BW kernel, x -> feat[BATCH][64] (full precision) ----------------
__global__ __launch_bounds__(256, 8) void stats_kernel(
    const float* __restrict__ x, const float* __restrict__ p,
    float* __restrict__ feat)
{
    const int t   = threadIdx.x;
    const int sub = t & 15;
    const int g0  = blockIdx.x * 16 + (t >> 4);
    const int NG  = gridDim.x * 16;
    for (int row = g0; row < BATCH * LEAD; row += NG) {
        int D  = row * MEM;
        int C0 = D >> 2, o0 = D & 3;
        int basei = 4 * sub - o0;
        float s = 0.f, ss = 0.f;
        if (basei < 51) {
            int ci = C0 + sub;
            if (4 * ci + 4 <= XTOTF) {
                f32x4 v = *(const f32x4*)(x + 4 * ci);
                #pragma unroll
                for (int i = 0; i < 4; ++i) {
                    bool ok = (basei + i >= 0) && (basei + i < 51);
                    float u = ok ? v[i] : 0.0f;
                    s += u; ss += u * u;
                }
            } else {
                #pragma unroll
                for (int i = 0; i < 4; ++i) {
                    int gi = 4 * ci + i;
                    bool ok = (basei + i >= 0) && (basei + i < 51) && (gi < XTOTF);
                    float u = ok ? x[gi] : 0.0f;
                    s += u; ss += u * u;
                }
            }
        }
        s += __shfl_xor(s, 1);  ss += __shfl_xor(ss, 1);
        s += __shfl_xor(s, 2);  ss += __shfl_xor(ss, 2);
        s += __shfl_xor(s, 4);  ss += __shfl_xor(ss, 4);
        s += __shfl_xor(s, 8);  ss += __shfl_xor(ss, 8);
        if (sub == 0) {
            int b = row / LEAD, ld = row - b * LEAD;
            float mv = s / 51.0f;
            float sd = sqrtf(fmaxf((ss - 51.0f * mv * mv) / 50.0f, 0.0f));
            float* fr = feat + (size_t)b * 64;
            fr[2 * ld]     = mv;
            fr[2 * ld + 1] = sd;
        }
    }
    for (size_t idx = (size_t)blockIdx.x * 256 + t; idx < (size_t)BATCH * 16;
         idx += (size_t)gridDim.x * 256) {
        int b = (int)(idx >> 4), c = (int)(idx & 15) + 48;
        feat[(size_t)b * 64 + c] = (c < 54) ? p[(size_t)b * NPRED + (c - 48)] : 0.0f;
    }
}

#define MFMA(a, b, c) __builtin_amdgcn_mfma_f32_16x16x32_bf16((a), (b), (c), 0, 0, 0)

// ---------------- spline body (fast-math) ----------------
__device__ __forceinline__ float spline_eval(const float* cc, float ff) {
    float dt_prod = 1.0f;
    #pragma unroll
    for (int blk = 0; blk < NBLK; ++blk) {
        float tk[5], yk[5];
        tk[0] = cc[blk * 10 + 0];
        yk[0] = cc[blk * 10 + 5];
        #pragma unroll
        for (int kk = 1; kk < 5; ++kk) {
            tk[kk] = tk[kk - 1] + 0.001f + sp_softplus(cc[blk * 10 + kk]);
            yk[kk] = yk[kk - 1] + 0.001f + sp_softplus(cc[blk * 10 + 5 + kk]);
        }
        float df[4];
        #pragma unroll
        for (int j = 0; j < 4; ++j) df[j] = __fdividef(yk[j + 1] - yk[j], tk[j + 1] - tk[j]);
        float g02 = __fdividef(yk[2] - yk[0], tk[2] - tk[0]);
        float g13 = __fdividef(yk[3] - yk[1], tk[3] - tk[1]);
        float g24 = __fdividef(yk[4] - yk[2], tk[4] - tk[2]);
        float dd[5];
        dd[0] = __fdividef(df[0] * df[0], g02);
        dd[1] = __fdividef(df[0] * df[1], g02);
        dd[2] = __fdividef(df[1] * df[2], g13);
        dd[3] = __fdividef(df[2] * df[3], g24);
        dd[4] = __fdividef(df[3] * df[3], g24);

        int cnt = (ff > tk[0]) + (ff > tk[1]) + (ff > tk[2]) + (ff > tk[3]) + (ff > tk[4]);
        bool e0 = (cnt == 0), e1 = (cnt == 5);
        int k0 = cnt - 1; k0 = k0 < 0 ? 0 : (k0 > 3 ? 3 : k0);

        float t0v = tk[0], t1v = tk[1], y0v = yk[0], y1v = yk[1], d0v = dd[0], d1v = dd[1];
        #pragma unroll
        for (int j = 1; j < 4; ++j) {
            bool c = (k0 == j);
            t0v = c ? tk[j] : t0v;  t1v = c ? tk[j + 1] : t1v;
            y0v = c ? yk[j] : y0v;  y1v = c ? yk[j + 1] : y1v;
            d0v = c ? dd[j] : d0v;  d1v = c ? dd[j + 1] : d1v;
        }

        float dt_ = t1v - t0v, dy_ = y1v - y0v;
        float s_  = __fdividef(dy_, dt_);
        float e   = __fdividef(ff - t0v, dt_);
        float one_e = 1.0f - e;
        float bb  = d1v + d0v - 2.0f * s_;
        float n0  = dy_ * (s_ * e * e + d0v * e * one_e);
        float n1  = s_ + bb * e * one_e;
        float p_mid = y0v + __fdividef(n0, n1);
        float p_lo  = d0v * ff + (y0v - d0v * t0v);
        float p_hi  = d1v * ff + (y1v - d1v * t1v);
        float val = e0 ? p_lo : (e1 ? p_hi : p_mid);

        float div0 = s_ * s_ * (d1v * e * e + 2.0f * s_ * e * one_e + d0v * one_e * one_e);
        float div1 = n1 * n1;
        float der  = e0 ? d0v : (e1 ? d1v : __fdividef(div0, div1));

        dt_prod *= der;
        ff = val;
    }
    return __expf(-0.5f * ff * ff) * dt_prod * 0.3989422804014327f;  // 1/sqrt(2pi)
}

// ---------------- barrier-free fused kernel: wave-private 16-row pipeline ----------------
// Round-22 configuration (measured best, 245 us): no barriers, no cbuf swizzle,
// direct LDS spline reads. r23/r24 proved both the s_barrier re-convergence and
// the swizzle+register-staging variants regress.
__global__ __launch_bounds__(256, 2) void fused_wave_kernel(
    const float* __restrict__ feat, const float* __restrict__ f,
    const float* __restrict__ b_in,
    const float* __restrict__ bs0, const float* __restrict__ bs1,
    const float* __restrict__ bs2, const float* __restrict__ bs3,
    const float* __restrict__ b_out,
    const unsigned short* __restrict__ wq,
    float* __restrict__ out)
{
    __shared__ __align__(16) char smem[4 * ARENA_B];

    const int t    = threadIdx.x;
    const int lane = t & 63;
    const int w    = t >> 6;
    const int lL   = lane & 15;
    const int lH   = lane >> 4;
    const int b0   = blockIdx.x * TB;
    const int r0   = b0 + w * 16;          // this wave's first global row

    short* hi_sh = (short*)(smem + w * ARENA_B);
    short* lo_sh = hi_sh + HPLW;
    float* cbufw = (float*)(smem + w * ARENA_B);
    unsigned* u32p = (unsigned*)hi_sh;

    // -------- phase 0': feat -> wave-private split-bf16 planes --------
    #pragma unroll
    for (int i = 0; i < 4; ++i) {
        int idx = i * 64 + lane;            // 0..255 : 16 rows x 16 chunks
        int r  = idx >> 4, c4 = (idx & 15) * 4;
        f32x4 v = *(const f32x4*)(feat + (size_t)(r0 + r) * 64 + c4);
        unsigned h0, l0, h1, l1, h2, l2, h3, l3;
        bf16split(v[0], h0, l0); bf16split(v[1], h1, l1);
        bf16split(v[2], h2, l2); bf16split(v[3], h3, l3);
        int base = r * HSTR + c4;           // even
        u32p[(base >> 1)]            = h0 | (h1 << 16);
        u32p[(base >> 1) + 1]        = h2 | (h3 << 16);
        u32p[((HPLW + base) >> 1)]     = l0 | (l1 << 16);
        u32p[((HPLW + base) >> 1) + 1] = l2 | (l3 << 16);
    }

    // -------- phases 1-2: 5 layers, wave-private --------
    #pragma unroll 1
    for (int L = 0; L < 5; ++L) {
        const unsigned short* wb;
        int loOff, KT;
        const float* bias;
        if (L == 0) { wb = wq;                      loOff = 8192;  KT = 2; bias = b_in; }
        else {
            wb = wq + 16384 + (L - 1) * 32768;      loOff = 16384; KT = 4;
            bias = (L == 1) ? bs0 : (L == 2) ? bs1 : (L == 3) ? bs2 : bs3;
        }

        s16x8 ah[4], al[4];
        #pragma unroll
        for (int kk = 0; kk < 4; ++kk) {
            if (kk < KT) {
                const short* ap = &hi_sh[lL * HSTR + kk * 32 + lH * 8];
                ah[kk] = *(const s16x8*)ap;
                al[kk] = *(const s16x8*)&lo_sh[lL * HSTR + kk * 32 + lH * 8];
            }
        }

        f32x4 acc[8];
        #pragma unroll
        for (int n = 0; n < 8; ++n) {
            f32x4 d = {0.f, 0.f, 0.f, 0.f};
            #pragma unroll
            for (int kk = 0; kk < 4; ++kk) {
                if (kk < KT) {
                    const unsigned short* bp_ = wb + ((n * KT + kk) * 64 + lane) * 8;
                    s16x8 bh = *(const s16x8*)bp_;
                    s16x8 bl = *(const s16x8*)(bp_ + loOff);
                    d = MFMA(ah[kk], bh, d);
                    d = MFMA(ah[kk], bl, d);
                    d = MFMA(al[kk], bh, d);
                }
            }
            acc[n] = d;
        }

        // writeback: silu(+skip) -> direct b16 stores
        #pragma unroll
        for (int n = 0; n < 8; ++n) {
            const int colb = n * 16 + lL;
            const float bv = bias[colb];
            #pragma unroll
            for (int r = 0; r < 4; ++r) {
                const int row = lH * 4 + r;
                float v = acc[n][r] + bv;
                float hnew;
                if (L > 0) {
                    float ho = bf16re(hi_sh[row * HSTR + colb]) + bf16re(lo_sh[row * HSTR + colb]);
                    hnew = silu_f(v) + ho;
                } else {
                    hnew = silu_f(v);
                }
                unsigned hi, lo; bf16split(hnew, hi, lo);
                hi_sh[row * HSTR + colb] = (short)hi;
                lo_sh[row * HSTR + colb] = (short)lo;
            }
        }
    }

    // -------- phase 3 + spline: wave-private, cbuf overlays arena --------
    s16x8 ah[4], al[4];
    #pragma unroll
    for (int kk = 0; kk < 4; ++kk) {
        ah[kk] = *(const s16x8*)&hi_sh[lL * HSTR + kk * 32 + lH * 8];
        al[kk] = *(const s16x8*)&lo_sh[lL * HSTR + kk * 32 + lH * 8];
    }

    const unsigned short* wop = wq + 147456;
    #pragma unroll 1
    for (int g = 0; g < 6; ++g) {
        #pragma unroll 2
        for (int nt10 = 0; nt10 < 10; ++nt10) {
            const int nt = g * 10 + nt10;
            f32x4 d = {0.f, 0.f, 0.f, 0.f};
            #pragma unroll
            for (int kk = 0; kk < 4; ++kk) {
                const unsigned short* bp_ = wop + ((nt * 4 + kk) * 64 + lane) * 8;
                s16x8 bh = *(const s16x8*)bp_;
                s16x8 bl = *(const s16x8*)(bp_ + 122880);
                d = MFMA(ah[kk], bh, d);
                d = MFMA(ah[kk], bl, d);
                d = MFMA(al[kk], bh, d);
            }
            const float bv = b_out[nt * 16 + lL];
            #pragma unroll
            for (int r = 0; r < 4; ++r)
                cbufw[(lH * 4 + r) * CSTRW + nt10 * 16 + lL] = d[r] + bv;
        }
        {
            const int r  = lane & 15;
            const int lg = lane >> 4;
            const float* cc = &cbufw[r * CSTRW + lg * 40];
            const size_t oi = (size_t)(r0 + r) * LEAD + g * 4 + lg;
            float ff = f[oi];
            out[oi] = spline_eval(cc, ff);
        }
    }
}

// ---------------- small-ws fallback: fully fused, x input ----------------
__device__ __forceinline__ void legacy_mlp(
    const float* __restrict__ x, const float* __restrict__ p,
    const float* __restrict__ b_in,
    const float* __restrict__ bs0, const float* __restrict__ bs1,
    const float* __restrict__ bs2, const float* __restrict__ bs3,
    const unsigned short* __restrict__ wq,
    short* hpl, int t, int lane, int w, int lL, int lH, int b0)
{
    {
        const int grp = lane >> 4, sub = lane & 15;
        for (int it = 0; it < (TB * LEAD) / 16; ++it) {
            int rowl = it * 16 + w * 4 + grp;
            int D   = (b0 * LEAD + rowl) * MEM;
            int C0  = D >> 2, o0 = D & 3;
            int basei = 4 * sub - o0;
            float s = 0.f, ss = 0.f;
            if (basei < 51) {
                f32x4 v = *(const f32x4*)(x + 4 * (C0 + sub));
                #pragma unroll
                for (int i = 0; i < 4; ++i) {
                    bool ok = (basei + i >= 0) && (basei + i < 51);
                    float u = ok ? v[i] : 0.0f;
                    s += u; ss += u * u;
                }
            }
            s += __shfl_xor(s, 1);  ss += __shfl_xor(ss, 1);
            s += __shfl_xor(s, 2);  ss += __shfl_xor(ss, 2);
            s += __shfl_xor(s, 4);  ss += __shfl_xor(ss, 4);
            s += __shfl_xor(s, 8);  ss += __shfl_xor(ss, 8);
            if (sub == 0) {
                int bl = rowl / LEAD, ld = rowl - bl * LEAD;
                float mv = s / 51.0f;
                float sd = sqrtf(fmaxf((ss - 51.0f * mv * mv) / 50.0f, 0.0f));
                unsigned hi, lo;
                bf16split(mv, hi, lo);
                hpl[bl * HSTR + 2 * ld] = (short)hi;  hpl[HPL + bl * HSTR + 2 * ld] = (short)lo;
                bf16split(sd, hi, lo);
                hpl[bl * HSTR + 2 * ld + 1] = (short)hi;  hpl[HPL + bl * HSTR + 2 * ld + 1] = (short)lo;
            }
        }
        for (int idx = t; idx < TB * NPRED; idx += 256) {
            int bl = idx / NPRED, j = idx - bl * NPRED;
            unsigned hi, lo;
            bf16split(p[(size_t)(b0 + bl) * NPRED + j], hi, lo);
            hpl[bl * HSTR + 48 + j] = (short)hi;  hpl[HPL + bl * HSTR + 48 + j] = (short)lo;
        }
        {
            int row = t >> 2;
            unsigned* u32p = (unsigned*)hpl;
            for (int c2 = 54 + 2 * (t & 3); c2 < 64; c2 += 8) {
                u32p[(row * HSTR + c2) >> 1] = 0u;
                u32p[(HPL + row * HSTR + c2) >> 1] = 0u;
            }
        }
    }
    __syncthreads();

    #pragma unroll 1
    for (int L = 0; L < 5; ++L) {
        const unsigned short* wb; int loOff, KT; const float* bias;
        if (L == 0) { wb = wq; loOff = 8192; KT = 2; bias = b_in; }
        else {
            wb = wq + 16384 + (L - 1) * 32768; loOff = 16384; KT = 4;
            bias = (L == 1) ? bs0 : (L == 2) ? bs1 : (L == 3) ? bs2 : bs3;
        }
        f32x4 acc[4][2];
        #pragma unroll
        for (int m = 0; m < 4; ++m)
            #pragma unroll
            for (int n = 0; n < 2; ++n) acc[m][n] = (f32x4){0.f, 0.f, 0.f, 0.f};
        #pragma unroll
        for (int n = 0; n < 2; ++n) {
            const int tile = w * 2 + n;
            #pragma unroll
            for (int kk = 0; kk < 4; ++kk) {
                if (kk < KT) {
                    const unsigned short* bp_ = wb + ((tile * KT + kk) * 64 + lane) * 8;
                    s16x8 bh = *(const s16x8*)bp_;
                    s16x8 bl = *(const s16x8*)(bp_ + loOff);
                    #pragma unroll
                    for (int m = 0; m < 4; ++m) {
                        const short* ap = &hpl[(m * 16 + lL) * HSTR + kk * 32 + lH * 8];
                        s16x8 ah = *(const s16x8*)ap;
                        s16x8 al = *(const s16x8*)(ap + HPL);
                        acc[m][n] = MFMA(ah, bh, acc[m][n]);
                        acc[m][n] = MFMA(ah, bl, acc[m][n]);
                        acc[m][n] = MFMA(al, bh, acc[m][n]);
                    }
                }
            }
        }
        __syncthreads();
        #pragma unroll
        for (int n = 0; n < 2; ++n) {
            const int colb = w * 32 + n * 16 + lL;
            const float bv = bias[colb];
            #pragma unroll
            for (int m = 0; m < 4; ++m) {
                #pragma unroll
                for (int r = 0; r < 4; ++r) {
                    const int row = m * 16 + lH * 4 + r;
                    float v = acc[m][n][r] + bv;
                    float hnew;
                    if (L > 0) {
                        float ho = bf16re(hpl[row * HSTR + colb]) + bf16re(hpl[HPL + row * HSTR + colb]);
                        hnew = silu_f(v) + ho;
                    } else {
                        hnew = silu_f(v);
                    }
                    unsigned hi, lo; bf16split(hnew, hi, lo);
                    hpl[row * HSTR + colb]       = (short)hi;
                    hpl[HPL + row * HSTR + colb] = (short)lo;
                }
            }
        }
        __syncthreads();
    }
}

__global__ __launch_bounds__(256, 2) void fused_mfma_kernel(
    const float* __restrict__ x, const float* __restrict__ p, const float* __restrict__ f,
    const float* __restrict__ b_in,
    const float* __restrict__ bs0, const float* __restrict__ bs1,
    const float* __restrict__ bs2, const float* __restrict__ bs3,
    const float* __restrict__ b_out,
    const unsigned short* __restrict__ wq,
    float* __restrict__ out)
{
    __shared__ short hpl[2 * HPL];
    __shared__ float cbuf[64 * CSTR];

    const int t    = threadIdx.x;
    const int lane = t & 63;
    const int w    = t >> 6;
    const int lL   = lane & 15;
    const int lH   = lane >> 4;
    const int b0   = blockIdx.x * TB;

    legacy_mlp(x, p, b_in, bs0, bs1, bs2, bs3, wq, hpl, t, lane, w, lL, lH, b0);

    const unsigned short* wop = wq + 147456;
    #pragma unroll 1
    for (int g = 0; g < 6; ++g) {
        #pragma unroll 1
        for (int nt = 0; nt < 10; ++nt) {
            const int colg = g * 160 + nt * 16 + lL;
            f32x4 d = {0.f, 0.f, 0.f, 0.f};
            #pragma unroll
            for (int kk = 0; kk < 4; ++kk) {
                const unsigned short* bp_ = wop + (((g * 10 + nt) * 4 + kk) * 64 + lane) * 8;
                s16x8 bh = *(const s16x8*)bp_;
                s16x8 bl = *(const s16x8*)(bp_ + 122880);
                const short* ap = &hpl[(w * 16 + lL) * HSTR + kk * 32 + lH * 8];
                s16x8 ah = *(const s16x8*)ap;
                s16x8 al = *(const s16x8*)(ap + HPL);
                d = MFMA(ah, bh, d);
                d = MFMA(ah, bl, d);
                d = MFMA(al, bh, d);
            }
            const float bv = b_out[colg];
            #pragma unroll
            for (int r = 0; r < 4; ++r)
                cbuf[(w * 16 + lH * 4 + r) * CSTR + nt * 16 + lL] = d[r] + bv;
        }
        __syncthreads();
        {
            const int b = t & 63, l = t >> 6;
            const float* cc = &cbuf[b * CSTR + l * 40];
            float ff = f[(size_t)(b0 + b) * LEAD + g * 4 + l];
            out[(size_t)(b0 + b) * LEAD + g * 4 + l] = spline_eval(cc, ff);
        }
        __syncthreads();
    }
}

extern "C" void kernel_launch(void* const* d_in, const int* in_sizes, int n_in,
                              void* d_out, int out_size, void* d_ws, size_t ws_size,
                              hipStream_t stream) {
    const float* x     = (const float*)d_in[0];
    const float* p     = (const float*)d_in[1];
    const float* f     = (const float*)d_in[2];
    const float* W_in  = (const float*)d_in[3];
    const float* b_in  = (const float*)d_in[4];
    const float* Ws0   = (const float*)d_in[5];
    const float* bs0   = (const float*)d_in[6];
    const float* Ws1   = (const float*)d_in[7];
    const float* bs1   = (const float*)d_in[8];
    const float* Ws2   = (const float*)d_in[9];
    const float* bs2   = (const float*)d_in[10];
    const float* Ws3   = (const float*)d_in[11];
    const float* bs3   = (const float*)d_in[12];
    const float* W_out = (const float*)d_in[13];
    const float* b_out = (const float*)d_in[14];
    float* out = (float*)d_out;

    unsigned short* wq = (unsigned short*)d_ws;
    float* feat = (float*)((char*)d_ws + WS_BYTES);

    if (ws_size >= WS_FUSED) {
        prep_kernel<<<768, 256, 0, stream>>>(W_in, Ws0, Ws1, Ws2, Ws3, W_out, wq);
        stats_kernel<<<2048, 256, 0, stream>>>(x, p, feat);
        fused_wave_kernel<<<BATCH / TB, 256, 0, stream>>>(
            feat, f, b_in, bs0, bs1, bs2, bs3, b_out, wq, out);
    } else if (ws_size >= (size_t)WS_BYTES) {
        prep_kernel<<<768, 256, 0, stream>>>(W_in, Ws0, Ws1, Ws2, Ws3, W_out, wq);
        fused_mfma_kernel<<<BATCH / TB, 256, 0, stream>>>(
            x, p, f, b_in, bs0, bs1, bs2, bs3, b_out, wq, out);
    }
}

// Round 26
// 235.268 us; speedup vs baseline: 1.2450x; 1.0300x over previous
//
#include <hip/hip_runtime.h>
#include <math.h>

#define BATCH 65536
#define LEAD  24
#define MEM   51
#define NPRED 6
#define HID   128
#define TB    64
#define NBLK  4
#define OUTC  960
#define XTOTF (BATCH * LEAD * MEM)

#define HSTR  136                 // bf16 plane row stride (shorts)
#define HPLW  (16 * HSTR)         // shorts per wave-plane (16 rows)
#define CSTRW 160                 // wave-kernel cbuf stride; 4 arenas = 40960 B -> 4 blocks/CU
#define ARENA_B (16 * CSTRW * 4)  // 10240 B
#define CSTR  165                 // legacy fallback cbuf stride
#define HPL   (64 * HSTR)         // legacy fallback plane size
// d_ws: [0, 786432) weights (frag-major) | [+FEAT_BYTES) feat f32 [BATCH][64]
#define WS_BYTES   786432
#define FEAT_BYTES ((size_t)BATCH * 64 * 4)
#define WS_FUSED   ((size_t)WS_BYTES + FEAT_BYTES)

typedef float f32x4 __attribute__((ext_vector_type(4)));
typedef short s16x8 __attribute__((ext_vector_type(8)));

// Fast-math forms (v_exp/v_log/v_rcp): rel err ~1e-6/op; absmax headroom is 8x.
__device__ __forceinline__ float sp_softplus(float z) {
    return fmaxf(z, 0.0f) + __logf(1.0f + __expf(-fabsf(z)));
}
__device__ __forceinline__ float silu_f(float z) {
    return __fdividef(z, 1.0f + __expf(-z));
}
__device__ __forceinline__ void bf16split(float x, unsigned &hi, unsigned &lo) {
    unsigned xb = __float_as_uint(x);
    hi = xb >> 16;
    float fhi = __uint_as_float(xb & 0xFFFF0000u);
    lo = __float_as_uint(x - fhi) >> 16;
}
__device__ __forceinline__ float bf16re(short u) {
    return __uint_as_float(((unsigned)(unsigned short)u) << 16);
}

// ---------------- prep: transpose + hi/lo split, fragment-major ----------------
__global__ __launch_bounds__(256) void prep_kernel(
    const float* __restrict__ W_in,
    const float* __restrict__ Ws0, const float* __restrict__ Ws1,
    const float* __restrict__ Ws2, const float* __restrict__ Ws3,
    const float* __restrict__ W_out, unsigned short* __restrict__ wq)
{
    int idx = blockIdx.x * 256 + threadIdx.x;
    float val; int ih, il;
    if (idx < 8192) {                  // W_inT: tile(8) x kt(2) x lane x j
        int tile = idx >> 10, rem = idx & 1023;
        int kk = rem >> 9, lane = (rem >> 3) & 63, j = rem & 7;
        int col = tile * 16 + (lane & 15);
        int k   = kk * 32 + (lane >> 4) * 8 + j;
        val = (k < 54) ? W_in[k * HID + col] : 0.0f;
        ih = idx; il = 8192 + idx;
    } else if (idx < 73728) {          // WsT: 4 layers x tile(8) x kt(4)
        int r = idx - 8192, l = r >> 14, r2 = r & 16383;
        int tile = r2 >> 11, rem = r2 & 2047;
        int kk = rem >> 9, lane = (rem >> 3) & 63, j = rem & 7;
        int col = tile * 16 + (lane & 15);
        int k   = kk * 32 + (lane >> 4) * 8 + j;
        const float* W = (l == 0) ? Ws0 : (l == 1) ? Ws1 : (l == 2) ? Ws2 : Ws3;
        val = W[k * HID + col];
        ih = 16384 + l * 32768 + r2; il = ih + 16384;
    } else {                           // W_outT: tile(60) x kt(4)
        int r = idx - 73728;
        int tile = r >> 11, rem = r & 2047;
        int kk = rem >> 9, lane = (rem >> 3) & 63, j = rem & 7;
        int col = tile * 16 + (lane & 15);
        int k   = kk * 32 + (lane >> 4) * 8 + j;
        val = W_out[k * OUTC + col];
        ih = 147456 + r; il = 270336 + r;
    }
    unsigned hi, lo; bf16split(val, hi, lo);
    wq[ih] = (unsigned short)hi;
    wq[il] = (unsigned short)lo;
}

// ---------------- stats: pure-BW kernel, x -> feat[BATCH][64] (full precision) ----------------
__global__ __launch_bounds__(256, 8) void stats_kernel(
    const float* __restrict__ x, const float* __restrict__ p,
    float* __restrict__ feat)
{
    const int t   = threadIdx.x;
    const int sub = t & 15;
    const int g0  = blockIdx.x * 16 + (t >> 4);
    const int NG  = gridDim.x * 16;
    for (int row = g0; row < BATCH * LEAD; row += NG) {
        int D  = row * MEM;
        int C0 = D >> 2, o0 = D & 3;
        int basei = 4 * sub - o0;
        float s = 0.f, ss = 0.f;
        if (basei < 51) {
            int ci = C0 + sub;
            if (4 * ci + 4 <= XTOTF) {
                f32x4 v = *(const f32x4*)(x + 4 * ci);
                #pragma unroll
                for (int i = 0; i < 4; ++i) {
                    bool ok = (basei + i >= 0) && (basei + i < 51);
                    float u = ok ? v[i] : 0.0f;
                    s += u; ss += u * u;
                }
            } else {
                #pragma unroll
                for (int i = 0; i < 4; ++i) {
                    int gi = 4 * ci + i;
                    bool ok = (basei + i >= 0) && (basei + i < 51) && (gi < XTOTF);
                    float u = ok ? x[gi] : 0.0f;
                    s += u; ss += u * u;
                }
            }
        }
        s += __shfl_xor(s, 1);  ss += __shfl_xor(ss, 1);
        s += __shfl_xor(s, 2);  ss += __shfl_xor(ss, 2);
        s += __shfl_xor(s, 4);  ss += __shfl_xor(ss, 4);
        s += __shfl_xor(s, 8);  ss += __shfl_xor(ss, 8);
        if (sub == 0) {
            int b = row / LEAD, ld = row - b * LEAD;
            float mv = s / 51.0f;
            float sd = sqrtf(fmaxf((ss - 51.0f * mv * mv) / 50.0f, 0.0f));
            float* fr = feat + (size_t)b * 64;
            fr[2 * ld]     = mv;
            fr[2 * ld + 1] = sd;
        }
    }
    for (size_t idx = (size_t)blockIdx.x * 256 + t; idx < (size_t)BATCH * 16;
         idx += (size_t)gridDim.x * 256) {
        int b = (int)(idx >> 4), c = (int)(idx & 15) + 48;
        feat[(size_t)b * 64 + c] = (c < 54) ? p[(size_t)b * NPRED + (c - 48)] : 0.0f;
    }
}

#define MFMA(a, b, c) __builtin_amdgcn_mfma_f32_16x16x32_bf16((a), (b), (c), 0, 0, 0)

// ---------------- spline body (fast-math) ----------------
__device__ __forceinline__ float spline_eval(const float* cc, float ff) {
    float dt_prod = 1.0f;
    #pragma unroll
    for (int blk = 0; blk < NBLK; ++blk) {
        float tk[5], yk[5];
        tk[0] = cc[blk * 10 + 0];
        yk[0] = cc[blk * 10 + 5];
        #pragma unroll
        for (int kk = 1; kk < 5; ++kk) {
            tk[kk] = tk[kk - 1] + 0.001f + sp_softplus(cc[blk * 10 + kk]);
            yk[kk] = yk[kk - 1] + 0.001f + sp_softplus(cc[blk * 10 + 5 + kk]);
        }
        float df[4];
        #pragma unroll
        for (int j = 0; j < 4; ++j) df[j] = __fdividef(yk[j + 1] - yk[j], tk[j + 1] - tk[j]);
        float g02 = __fdividef(yk[2] - yk[0], tk[2] - tk[0]);
        float g13 = __fdividef(yk[3] - yk[1], tk[3] - tk[1]);
        float g24 = __fdividef(yk[4] - yk[2], tk[4] - tk[2]);
        float dd[5];
        dd[0] = __fdividef(df[0] * df[0], g02);
        dd[1] = __fdividef(df[0] * df[1], g02);
        dd[2] = __fdividef(df[1] * df[2], g13);
        dd[3] = __fdividef(df[2] * df[3], g24);
        dd[4] = __fdividef(df[3] * df[3], g24);

        int cnt = (ff > tk[0]) + (ff > tk[1]) + (ff > tk[2]) + (ff > tk[3]) + (ff > tk[4]);
        bool e0 = (cnt == 0), e1 = (cnt == 5);
        int k0 = cnt - 1; k0 = k0 < 0 ? 0 : (k0 > 3 ? 3 : k0);

        float t0v = tk[0], t1v = tk[1], y0v = yk[0], y1v = yk[1], d0v = dd[0], d1v = dd[1];
        #pragma unroll
        for (int j = 1; j < 4; ++j) {
            bool c = (k0 == j);
            t0v = c ? tk[j] : t0v;  t1v = c ? tk[j + 1] : t1v;
            y0v = c ? yk[j] : y0v;  y1v = c ? yk[j + 1] : y1v;
            d0v = c ? dd[j] : d0v;  d1v = c ? dd[j + 1] : d1v;
        }

        float dt_ = t1v - t0v, dy_ = y1v - y0v;
        float s_  = __fdividef(dy_, dt_);
        float e   = __fdividef(ff - t0v, dt_);
        float one_e = 1.0f - e;
        float bb  = d1v + d0v - 2.0f * s_;
        float n0  = dy_ * (s_ * e * e + d0v * e * one_e);
        float n1  = s_ + bb * e * one_e;
        float p_mid = y0v + __fdividef(n0, n1);
        float p_lo  = d0v * ff + (y0v - d0v * t0v);
        float p_hi  = d1v * ff + (y1v - d1v * t1v);
        float val = e0 ? p_lo : (e1 ? p_hi : p_mid);

        float div0 = s_ * s_ * (d1v * e * e + 2.0f * s_ * e * one_e + d0v * one_e * one_e);
        float div1 = n1 * n1;
        float der  = e0 ? d0v : (e1 ? d1v : __fdividef(div0, div1));

        dt_prod *= der;
        ff = val;
    }
    return __expf(-0.5f * ff * ff) * dt_prod * 0.3989422804014327f;  // 1/sqrt(2pi)
}

// ---------------- barrier-free fused kernel: wave-private 16-row pipeline ----------------
// r22 structure + register-resident skip: h for this lane's (row,col) slots
// lives in hreg[8][4] across layers (the (lane,n,r)->(row,col) map is layer-
// invariant), so the skip-add is a register add instead of 2x ds_read_u16+cvt.
// bf16 planes still written (next layer's cross-lane A-frags need them).
__global__ __launch_bounds__(256, 2) void fused_wave_kernel(
    const float* __restrict__ feat, const float* __restrict__ f,
    const float* __restrict__ b_in,
    const float* __restrict__ bs0, const float* __restrict__ bs1,
    const float* __restrict__ bs2, const float* __restrict__ bs3,
    const float* __restrict__ b_out,
    const unsigned short* __restrict__ wq,
    float* __restrict__ out)
{
    __shared__ __align__(16) char smem[4 * ARENA_B];

    const int t    = threadIdx.x;
    const int lane = t & 63;
    const int w    = t >> 6;
    const int lL   = lane & 15;
    const int lH   = lane >> 4;
    const int b0   = blockIdx.x * TB;
    const int r0   = b0 + w * 16;          // this wave's first global row

    short* hi_sh = (short*)(smem + w * ARENA_B);
    short* lo_sh = hi_sh + HPLW;
    float* cbufw = (float*)(smem + w * ARENA_B);
    unsigned* u32p = (unsigned*)hi_sh;

    // -------- phase 0': feat -> wave-private split-bf16 planes --------
    #pragma unroll
    for (int i = 0; i < 4; ++i) {
        int idx = i * 64 + lane;            // 0..255 : 16 rows x 16 chunks
        int r  = idx >> 4, c4 = (idx & 15) * 4;
        f32x4 v = *(const f32x4*)(feat + (size_t)(r0 + r) * 64 + c4);
        unsigned h0, l0, h1, l1, h2, l2, h3, l3;
        bf16split(v[0], h0, l0); bf16split(v[1], h1, l1);
        bf16split(v[2], h2, l2); bf16split(v[3], h3, l3);
        int base = r * HSTR + c4;           // even
        u32p[(base >> 1)]            = h0 | (h1 << 16);
        u32p[(base >> 1) + 1]        = h2 | (h3 << 16);
        u32p[((HPLW + base) >> 1)]     = l0 | (l1 << 16);
        u32p[((HPLW + base) >> 1) + 1] = l2 | (l3 << 16);
    }

    // -------- phases 1-2: 5 layers, wave-private, h skip in registers --------
    float hreg[8][4];   // this lane's h at (row=lH*4+r, col=n*16+lL)

    #pragma unroll 1
    for (int L = 0; L < 5; ++L) {
        const unsigned short* wb;
        int loOff, KT;
        const float* bias;
        if (L == 0) { wb = wq;                      loOff = 8192;  KT = 2; bias = b_in; }
        else {
            wb = wq + 16384 + (L - 1) * 32768;      loOff = 16384; KT = 4;
            bias = (L == 1) ? bs0 : (L == 2) ? bs1 : (L == 3) ? bs2 : bs3;
        }

        s16x8 ah[4], al[4];
        #pragma unroll
        for (int kk = 0; kk < 4; ++kk) {
            if (kk < KT) {
                const short* ap = &hi_sh[lL * HSTR + kk * 32 + lH * 8];
                ah[kk] = *(const s16x8*)ap;
                al[kk] = *(const s16x8*)&lo_sh[lL * HSTR + kk * 32 + lH * 8];
            }
        }

        f32x4 acc[8];
        #pragma unroll
        for (int n = 0; n < 8; ++n) {
            f32x4 d = {0.f, 0.f, 0.f, 0.f};
            #pragma unroll
            for (int kk = 0; kk < 4; ++kk) {
                if (kk < KT) {
                    const unsigned short* bp_ = wb + ((n * KT + kk) * 64 + lane) * 8;
                    s16x8 bh = *(const s16x8*)bp_;
                    s16x8 bl = *(const s16x8*)(bp_ + loOff);
                    d = MFMA(ah[kk], bh, d);
                    d = MFMA(ah[kk], bl, d);
                    d = MFMA(al[kk], bh, d);
                }
            }
            acc[n] = d;
        }

        // writeback: silu(+register skip) -> direct b16 stores
        #pragma unroll
        for (int n = 0; n < 8; ++n) {
            const int colb = n * 16 + lL;
            const float bv = bias[colb];
            #pragma unroll
            for (int r = 0; r < 4; ++r) {
                const int row = lH * 4 + r;
                float v = acc[n][r] + bv;
                float hnew = (L > 0) ? (silu_f(v) + hreg[n][r]) : silu_f(v);
                hreg[n][r] = hnew;
                unsigned hi, lo; bf16split(hnew, hi, lo);
                hi_sh[row * HSTR + colb] = (short)hi;
                lo_sh[row * HSTR + colb] = (short)lo;
            }
        }
    }

    // -------- phase 3 + spline: wave-private, cbuf overlays arena --------
    s16x8 ah[4], al[4];
    #pragma unroll
    for (int kk = 0; kk < 4; ++kk) {
        ah[kk] = *(const s16x8*)&hi_sh[lL * HSTR + kk * 32 + lH * 8];
        al[kk] = *(const s16x8*)&lo_sh[lL * HSTR + kk * 32 + lH * 8];
    }

    const unsigned short* wop = wq + 147456;
    #pragma unroll 1
    for (int g = 0; g < 6; ++g) {
        #pragma unroll 2
        for (int nt10 = 0; nt10 < 10; ++nt10) {
            const int nt = g * 10 + nt10;
            f32x4 d = {0.f, 0.f, 0.f, 0.f};
            #pragma unroll
            for (int kk = 0; kk < 4; ++kk) {
                const unsigned short* bp_ = wop + ((nt * 4 + kk) * 64 + lane) * 8;
                s16x8 bh = *(const s16x8*)bp_;
                s16x8 bl = *(const s16x8*)(bp_ + 122880);
                d = MFMA(ah[kk], bh, d);
                d = MFMA(ah[kk], bl, d);
                d = MFMA(al[kk], bh, d);
            }
            const float bv = b_out[nt * 16 + lL];
            #pragma unroll
            for (int r = 0; r < 4; ++r)
                cbufw[(lH * 4 + r) * CSTRW + nt10 * 16 + lL] = d[r] + bv;
        }
        {
            const int r  = lane & 15;
            const int lg = lane >> 4;
            const float* cc = &cbufw[r * CSTRW + lg * 40];
            const size_t oi = (size_t)(r0 + r) * LEAD + g * 4 + lg;
            float ff = f[oi];
            out[oi] = spline_eval(cc, ff);
        }
    }
}

// ---------------- small-ws fallback: fully fused, x input ----------------
__device__ __forceinline__ void legacy_mlp(
    const float* __restrict__ x, const float* __restrict__ p,
    const float* __restrict__ b_in,
    const float* __restrict__ bs0, const float* __restrict__ bs1,
    const float* __restrict__ bs2, const float* __restrict__ bs3,
    const unsigned short* __restrict__ wq,
    short* hpl, int t, int lane, int w, int lL, int lH, int b0)
{
    {
        const int grp = lane >> 4, sub = lane & 15;
        for (int it = 0; it < (TB * LEAD) / 16; ++it) {
            int rowl = it * 16 + w * 4 + grp;
            int D   = (b0 * LEAD + rowl) * MEM;
            int C0  = D >> 2, o0 = D & 3;
            int basei = 4 * sub - o0;
            float s = 0.f, ss = 0.f;
            if (basei < 51) {
                f32x4 v = *(const f32x4*)(x + 4 * (C0 + sub));
                #pragma unroll
                for (int i = 0; i < 4; ++i) {
                    bool ok = (basei + i >= 0) && (basei + i < 51);
                    float u = ok ? v[i] : 0.0f;
                    s += u; ss += u * u;
                }
            }
            s += __shfl_xor(s, 1);  ss += __shfl_xor(ss, 1);
            s += __shfl_xor(s, 2);  ss += __shfl_xor(ss, 2);
            s += __shfl_xor(s, 4);  ss += __shfl_xor(ss, 4);
            s += __shfl_xor(s, 8);  ss += __shfl_xor(ss, 8);
            if (sub == 0) {
                int bl = rowl / LEAD, ld = rowl - bl * LEAD;
                float mv = s / 51.0f;
                float sd = sqrtf(fmaxf((ss - 51.0f * mv * mv) / 50.0f, 0.0f));
                unsigned hi, lo;
                bf16split(mv, hi, lo);
                hpl[bl * HSTR + 2 * ld] = (short)hi;  hpl[HPL + bl * HSTR + 2 * ld] = (short)lo;
                bf16split(sd, hi, lo);
                hpl[bl * HSTR + 2 * ld + 1] = (short)hi;  hpl[HPL + bl * HSTR + 2 * ld + 1] = (short)lo;
            }
        }
        for (int idx = t; idx < TB * NPRED; idx += 256) {
            int bl = idx / NPRED, j = idx - bl * NPRED;
            unsigned hi, lo;
            bf16split(p[(size_t)(b0 + bl) * NPRED + j], hi, lo);
            hpl[bl * HSTR + 48 + j] = (short)hi;  hpl[HPL + bl * HSTR + 48 + j] = (short)lo;
        }
        {
            int row = t >> 2;
            unsigned* u32p = (unsigned*)hpl;
            for (int c2 = 54 + 2 * (t & 3); c2 < 64; c2 += 8) {
                u32p[(row * HSTR + c2) >> 1] = 0u;
                u32p[(HPL + row * HSTR + c2) >> 1] = 0u;
            }
        }
    }
    __syncthreads();

    #pragma unroll 1
    for (int L = 0; L < 5; ++L) {
        const unsigned short* wb; int loOff, KT; const float* bias;
        if (L == 0) { wb = wq; loOff = 8192; KT = 2; bias = b_in; }
        else {
            wb = wq + 16384 + (L - 1) * 32768; loOff = 16384; KT = 4;
            bias = (L == 1) ? bs0 : (L == 2) ? bs1 : (L == 3) ? bs2 : bs3;
        }
        f32x4 acc[4][2];
        #pragma unroll
        for (int m = 0; m < 4; ++m)
            #pragma unroll
            for (int n = 0; n < 2; ++n) acc[m][n] = (f32x4){0.f, 0.f, 0.f, 0.f};
        #pragma unroll
        for (int n = 0; n < 2; ++n) {
            const int tile = w * 2 + n;
            #pragma unroll
            for (int kk = 0; kk < 4; ++kk) {
                if (kk < KT) {
                    const unsigned short* bp_ = wb + ((tile * KT + kk) * 64 + lane) * 8;
                    s16x8 bh = *(const s16x8*)bp_;
                    s16x8 bl = *(const s16x8*)(bp_ + loOff);
                    #pragma unroll
                    for (int m = 0; m < 4; ++m) {
                        const short* ap = &hpl[(m * 16 + lL) * HSTR + kk * 32 + lH * 8];
                        s16x8 ah = *(const s16x8*)ap;
                        s16x8 al = *(const s16x8*)(ap + HPL);
                        acc[m][n] = MFMA(ah, bh, acc[m][n]);
                        acc[m][n] = MFMA(ah, bl, acc[m][n]);
                        acc[m][n] = MFMA(al, bh, acc[m][n]);
                    }
                }
            }
        }
        __syncthreads();
        #pragma unroll
        for (int n = 0; n < 2; ++n) {
            const int colb = w * 32 + n * 16 + lL;
            const float bv = bias[colb];
            #pragma unroll
            for (int m = 0; m < 4; ++m) {
                #pragma unroll
                for (int r = 0; r < 4; ++r) {
                    const int row = m * 16 + lH * 4 + r;
                    float v = acc[m][n][r] + bv;
                    float hnew;
                    if (L > 0) {
                        float ho = bf16re(hpl[row * HSTR + colb]) + bf16re(hpl[HPL + row * HSTR + colb]);
                        hnew = silu_f(v) + ho;
                    } else {
                        hnew = silu_f(v);
                    }
                    unsigned hi, lo; bf16split(hnew, hi, lo);
                    hpl[row * HSTR + colb]       = (short)hi;
                    hpl[HPL + row * HSTR + colb] = (short)lo;
                }
            }
        }
        __syncthreads();
    }
}

__global__ __launch_bounds__(256, 2) void fused_mfma_kernel(
    const float* __restrict__ x, const float* __restrict__ p, const float* __restrict__ f,
    const float* __restrict__ b_in,
    const float* __restrict__ bs0, const float* __restrict__ bs1,
    const float* __restrict__ bs2, const float* __restrict__ bs3,
    const float* __restrict__ b_out,
    const unsigned short* __restrict__ wq,
    float* __restrict__ out)
{
    __shared__ short hpl[2 * HPL];
    __shared__ float cbuf[64 * CSTR];

    const int t    = threadIdx.x;
    const int lane = t & 63;
    const int w    = t >> 6;
    const int lL   = lane & 15;
    const int lH   = lane >> 4;
    const int b0   = blockIdx.x * TB;

    legacy_mlp(x, p, b_in, bs0, bs1, bs2, bs3, wq, hpl, t, lane, w, lL, lH, b0);

    const unsigned short* wop = wq + 147456;
    #pragma unroll 1
    for (int g = 0; g < 6; ++g) {
        #pragma unroll 1
        for (int nt = 0; nt < 10; ++nt) {
            const int colg = g * 160 + nt * 16 + lL;
            f32x4 d = {0.f, 0.f, 0.f, 0.f};
            #pragma unroll
            for (int kk = 0; kk < 4; ++kk) {
                const unsigned short* bp_ = wop + (((g * 10 + nt) * 4 + kk) * 64 + lane) * 8;
                s16x8 bh = *(const s16x8*)bp_;
                s16x8 bl = *(const s16x8*)(bp_ + 122880);
                const short* ap = &hpl[(w * 16 + lL) * HSTR + kk * 32 + lH * 8];
                s16x8 ah = *(const s16x8*)ap;
                s16x8 al = *(const s16x8*)(ap + HPL);
                d = MFMA(ah, bh, d);
                d = MFMA(ah, bl, d);
                d = MFMA(al, bh, d);
            }
            const float bv = b_out[colg];
            #pragma unroll
            for (int r = 0; r < 4; ++r)
                cbuf[(w * 16 + lH * 4 + r) * CSTR + nt * 16 + lL] = d[r] + bv;
        }
        __syncthreads();
        {
            const int b = t & 63, l = t >> 6;
            const float* cc = &cbuf[b * CSTR + l * 40];
            float ff = f[(size_t)(b0 + b) * LEAD + g * 4 + l];
            out[(size_t)(b0 + b) * LEAD + g * 4 + l] = spline_eval(cc, ff);
        }
        __syncthreads();
    }
}

extern "C" void kernel_launch(void* const* d_in, const int* in_sizes, int n_in,
                              void* d_out, int out_size, void* d_ws, size_t ws_size,
                              hipStream_t stream) {
    const float* x     = (const float*)d_in[0];
    const float* p     = (const float*)d_in[1];
    const float* f     = (const float*)d_in[2];
    const float* W_in  = (const float*)d_in[3];
    const float* b_in  = (const float*)d_in[4];
    const float* Ws0   = (const float*)d_in[5];
    const float* bs0   = (const float*)d_in[6];
    const float* Ws1   = (const float*)d_in[7];
    const float* bs1   = (const float*)d_in[8];
    const float* Ws2   = (const float*)d_in[9];
    const float* bs2   = (const float*)d_in[10];
    const float* Ws3   = (const float*)d_in[11];
    const float* bs3   = (const float*)d_in[12];
    const float* W_out = (const float*)d_in[13];
    const float* b_out = (const float*)d_in[14];
    float* out = (float*)d_out;

    unsigned short* wq = (unsigned short*)d_ws;
    float* feat = (float*)((char*)d_ws + WS_BYTES);

    if (ws_size >= WS_FUSED) {
        prep_kernel<<<768, 256, 0, stream>>>(W_in, Ws0, Ws1, Ws2, Ws3, W_out, wq);
        stats_kernel<<<2048, 256, 0, stream>>>(x, p, feat);
        fused_wave_kernel<<<BATCH / TB, 256, 0, stream>>>(
            feat, f, b_in, bs0, bs1, bs2, bs3, b_out, wq, out);
    } else if (ws_size >= (size_t)WS_BYTES) {
        prep_kernel<<<768, 256, 0, stream>>>(W_in, Ws0, Ws1, Ws2, Ws3, W_out, wq);
        fused_mfma_kernel<<<BATCH / TB, 256, 0, stream>>>(
            x, p, f, b_in, bs0, bs1, bs2, bs3, b_out, wq, out);
    }
}